// Round 6
// baseline (374.235 us; speedup 1.0000x reference)
//
#include <hip/hip_runtime.h>
#include <math.h>

// CILRS fused head — round 13.
//  Base = round 12 (164 µs k_fused). Register wall (64 VGPR + 64 AGPR = 128 cap)
//  blocks deeper pipelining; instead halve the latency-bound PK stream again:
//   - 128 rows/block, 1024 threads (16 waves), 133 KB LDS tile, 1 block/CU
//     (same 16 waves/CU as r12). PK traffic 1.1 GB -> 0.55 GB; 8 MFMA / B-load.
//   - phase 1 in two 64-row passes; phase 3 paired-mt A-loads; phase 4 halves.
//   - keep: NT emb loads, setprio around MFMA, parallel count, NT out stores.

#define B_ 65536
#define D_ 512
#define H_ 256

typedef float  f32x4   __attribute__((ext_vector_type(4)));
typedef __bf16 bf16x8  __attribute__((ext_vector_type(8)));
typedef __bf16 bf16x4  __attribute__((ext_vector_type(4)));
typedef float  float4v __attribute__((ext_vector_type(4)));

// ---- ws layout (bytes) ----
// [0..23]  counts[6]   (zeroed by hipMemsetAsync)
// [24..47] cursor2[6]  (zeroed by hipMemsetAsync)
#define OFF_PERM     256        // 65536 ints
#define OFF_PACK     262400     // packed bf16 weights (3,014,656 B)
#define WS_NEEDED    3277056

// packed element offsets (bf16 elements, relative to PK); layout [kc][n][32k]
#define PKO_SW2   0u
#define PKO_BW1   131072u
#define PKO_BW2   917504u
#define PKO_OW1   1310720u
#define PKO_OW2   1441792u

#define PITCH_E 520   // row pitch (bf16) for the 128x512 tile

// ---------------- prep 1: 64-block histogram ----------------

__global__ __launch_bounds__(256) void k_count(const int* __restrict__ command,
                                               int* __restrict__ counts) {
    __shared__ int lh[6];
    int t = threadIdx.x;
    if (t < 6) lh[t] = 0;
    __syncthreads();
    int i = blockIdx.x * 256 + t;
    int4 v = ((const int4*)command)[i];
    int a[4] = {v.x, v.y, v.z, v.w};
    #pragma unroll
    for (int j = 0; j < 4; ++j) {
        int c = min(max(a[j] - 1, 0), 5);
        atomicAdd(&lh[c], 1);
    }
    __syncthreads();
    if (t < 6) atomicAdd(&counts[t], lh[t]);
}

// ---------------- prep 2: scatter + pack fused ----------------

__global__ __launch_bounds__(256) void k_prepB(const int* __restrict__ command,
                                               const int* __restrict__ counts,
                                               int* __restrict__ cursor2,
                                               int* __restrict__ perm,
                                               const float* __restrict__ sw2,
                                               const float* __restrict__ bw1,
                                               const float* __restrict__ bw2,
                                               const float* __restrict__ ow1,
                                               const float* __restrict__ ow2,
                                               __bf16* __restrict__ PK) {
    int t = threadIdx.x;
    if (blockIdx.x < 256) {
        // ---- scatter ----
        __shared__ int lh[6], lbase[6];
        if (t < 6) lh[t] = 0;
        __syncthreads();
        int i = blockIdx.x * 256 + t;
        int c = command[i] - 1; c = min(max(c, 0), 5);
        int rank = atomicAdd(&lh[c], 1);
        __syncthreads();
        if (t < 6) {
            int base = 0;
            #pragma unroll
            for (int k = 0; k < 6; ++k) base += (k < t) ? counts[k] : 0;
            lbase[t] = base + atomicAdd(&cursor2[t], lh[t]);
        }
        __syncthreads();
        perm[lbase[c] + rank] = i;
        return;
    }
    // ---- pack: W [C][K][N] fp32 -> PK bf16 [kc][n][32k] ----
    int b = blockIdx.x - 256;
    const float* src; int srcN, colOff; unsigned dstOff; int tt;
    if (b < 64)       { int s = b >> 5;        tt = b & 31;  src = sw2;                          srcN = 512; colOff = s * 256; dstOff = PKO_SW2 + s * 65536u; }
    else if (b < 448) { int i = b - 64;  int c = i >> 6; tt = i & 63; src = bw1 + (size_t)c * 512 * 256; srcN = 256; colOff = 0; dstOff = PKO_BW1 + c * 131072u; }
    else if (b < 640) { int i = b - 448; int c = i >> 5; tt = i & 31; src = bw2 + (size_t)c * 256 * 256; srcN = 256; colOff = 0; dstOff = PKO_BW2 + c * 65536u; }
    else if (b < 704) { tt = b - 640; src = ow1; srcN = 256; colOff = 0; dstOff = PKO_OW1; }
    else              { tt = b - 704; src = ow2; srcN = 256; colOff = 0; dstOff = PKO_OW2; }
    int kc = tt >> 2, nt = tt & 3;
    int k0 = kc * 32, n0 = nt * 64;

    __shared__ __bf16 T[64][34];
    #pragma unroll
    for (int p = 0; p < 2; ++p) {
        int idx = p * 256 + t;            // 512 chunks: 32 k x 16 n4
        int k = idx >> 4, n4 = idx & 15;
        float4v v = *(const float4v*)(src + (size_t)(k0 + k) * srcN + colOff + n0 + n4 * 4);
        T[n4 * 4 + 0][k] = (__bf16)v[0];
        T[n4 * 4 + 1][k] = (__bf16)v[1];
        T[n4 * 4 + 2][k] = (__bf16)v[2];
        T[n4 * 4 + 3][k] = (__bf16)v[3];
    }
    __syncthreads();
    int n = t >> 2, seg = t & 3;
    bf16x8 v;
    #pragma unroll
    for (int j = 0; j < 8; ++j) v[j] = T[n][seg * 8 + j];
    *(bf16x8*)(PK + dstOff + ((unsigned)(kc * 256 + n0 + n) * 32u + seg * 8u)) = v;
}

// ---------------- fused main: 128 rows/block, 16 waves, 128x512 LDS tile ----------------

__global__ __launch_bounds__(1024, 4) void k_fused(
    const float* __restrict__ embedding, const float* __restrict__ speed,
    const int*   __restrict__ command,
    const float* __restrict__ sw1, const float* __restrict__ sb1,
    const float* __restrict__ sb2,
    const float* __restrict__ bb1, const float* __restrict__ bb2,
    const float* __restrict__ bw3, const float* __restrict__ bb3,
    const float* __restrict__ ob1, const float* __restrict__ ob2,
    const float* __restrict__ ow3, const float* __restrict__ ob3,
    const int* __restrict__ perm, const __bf16* __restrict__ PK,
    float* __restrict__ out)
{
    __shared__ __bf16 s_x[128 * PITCH_E];    // 133.1 KB: emb, then [h1|t1]
    __shared__ float  s_head[128][4];
    __shared__ int    s_row[128];
    __shared__ int    s_cmd[128];
    __shared__ float  s_spd[128];

    const int tid = threadIdx.x;
    const int w = tid >> 6, lane = tid & 63;
    const int lm = lane & 15, kg = lane >> 4;
    const int R0 = blockIdx.x * 128;

    if (tid < 128) {
        int r = perm[R0 + tid];
        s_row[tid] = r;
        int c = command[r] - 1; c = min(max(c, 0), 5);
        s_cmd[tid] = c;
        s_spd[tid] = speed[r];
        s_head[tid][0] = 0.f; s_head[tid][1] = 0.f; s_head[tid][2] = 0.f; s_head[tid][3] = 0.f;
    }
    __syncthreads();

    // ---- stage embedding -> LDS bf16 (NT: evict-first, protect PK in L2) ----
    #pragma unroll
    for (int it = 0; it < 16; ++it) {
        int idx = it * 1024 + tid;         // 16384 chunks: 128 rows x 128
        int row = idx >> 7, c4 = idx & 127;
        float4v v = __builtin_nontemporal_load(
            (const float4v*)(embedding + (size_t)s_row[row] * D_ + c4 * 4));
        bf16x4 pv;
        pv[0] = (__bf16)v[0]; pv[1] = (__bf16)v[1];
        pv[2] = (__bf16)v[2]; pv[3] = (__bf16)v[3];
        *(bf16x4*)(s_x + row * PITCH_E + c4 * 4) = pv;
    }
    __syncthreads();

    const int cmin = s_cmd[0], cmax = s_cmd[127];   // perm is bucket-sorted

    // ---- transposed speedMLP: deltaT = sw2T @ shT; two 64-row passes ----
    // wave w owns emb cols w*32..+32 (2 M-tiles); per pass N = 64 rows (4 N-tiles)
    {
        const unsigned slice = (unsigned)(w >> 3) * 65536u;
        const int mbase = (w & 7) * 32;
        #pragma unroll
        for (int p = 0; p < 2; ++p) {
            float spd[4];
            #pragma unroll
            for (int nt = 0; nt < 4; ++nt) spd[nt] = s_spd[p * 64 + nt * 16 + lm];
            f32x4 dacc[2][4];
            #pragma unroll
            for (int mt = 0; mt < 2; ++mt)
                #pragma unroll
                for (int nt = 0; nt < 4; ++nt) dacc[mt][nt] = f32x4{0.f, 0.f, 0.f, 0.f};
            #pragma unroll 2
            for (int ks = 0; ks < 8; ++ks) {
                const int k0 = ks * 32 + kg * 8;
                float4v w0 = *(const float4v*)(sw1 + k0);
                float4v w1 = *(const float4v*)(sw1 + k0 + 4);
                float4v c0 = *(const float4v*)(sb1 + k0);
                float4v c1 = *(const float4v*)(sb1 + k0 + 4);
                bf16x8 bns[4];
                #pragma unroll
                for (int nt = 0; nt < 4; ++nt)
                    #pragma unroll
                    for (int j = 0; j < 4; ++j) {
                        bns[nt][j]     = (__bf16)fmaxf(spd[nt] * w0[j] + c0[j], 0.f);
                        bns[nt][j + 4] = (__bf16)fmaxf(spd[nt] * w1[j] + c1[j], 0.f);
                    }
                const __bf16* ap = PK + PKO_SW2 + slice + (size_t)ks * 8192
                                 + (size_t)(mbase + lm) * 32 + kg * 8;
                __builtin_amdgcn_s_setprio(1);
                #pragma unroll
                for (int mt = 0; mt < 2; ++mt) {
                    bf16x8 av = *(const bf16x8*)(ap + mt * 512);
                    #pragma unroll
                    for (int nt = 0; nt < 4; ++nt)
                        dacc[mt][nt] = __builtin_amdgcn_mfma_f32_16x16x32_bf16(av, bns[nt], dacc[mt][nt], 0, 0, 0);
                }
                __builtin_amdgcn_s_setprio(0);
            }
            #pragma unroll
            for (int mt = 0; mt < 2; ++mt) {
                int colb = w * 32 + mt * 16 + kg * 4;
                float4v sbv = *(const float4v*)(sb2 + colb);
                #pragma unroll
                for (int nt = 0; nt < 4; ++nt) {
                    int row = p * 64 + nt * 16 + lm;
                    bf16x4* ptr = (bf16x4*)(s_x + row * PITCH_E + colb);
                    bf16x4 old = *ptr;
                    bf16x4 nv;
                    #pragma unroll
                    for (int g = 0; g < 4; ++g)
                        nv[g] = (__bf16)(dacc[mt][nt][g] + sbv[g] + (float)old[g]);
                    *ptr = nv;
                }
            }
        }
    }
    __syncthreads();

    const bool roleB = (w < 8);
    const int colbase = (w & 7) * 32;
    const unsigned laneoffB = (unsigned)(colbase + lm) * 32u + kg * 8u;
    const __bf16* aXbase = s_x + lm * PITCH_E + kg * 8;   // + mt*16*PITCH_E

    // ---- phase 3: h1 (waves 0-7, c-loop) | t1 (waves 8-15); results in regs ----
    bf16x4 res[8][2];   // [mt][ct]
    if (roleB) {
        for (int c = cmin; c <= cmax; ++c) {
            const __bf16* bb = PK + PKO_BW1 + (unsigned)c * 131072u + laneoffB;
            f32x4 ah[8][2];
            #pragma unroll
            for (int mt = 0; mt < 8; ++mt) {
                ah[mt][0] = f32x4{0.f, 0.f, 0.f, 0.f};
                ah[mt][1] = f32x4{0.f, 0.f, 0.f, 0.f};
            }
            #pragma unroll 2
            for (int ks = 0; ks < 16; ++ks) {
                bf16x8 bv0 = *(const bf16x8*)(bb + (size_t)ks * 8192);
                bf16x8 bv1 = *(const bf16x8*)(bb + (size_t)ks * 8192 + 512);
                __builtin_amdgcn_s_setprio(1);
                #pragma unroll
                for (int mp = 0; mp < 4; ++mp) {
                    bf16x8 a0 = *(const bf16x8*)(aXbase + (2 * mp + 0) * 16 * PITCH_E + ks * 32);
                    bf16x8 a1 = *(const bf16x8*)(aXbase + (2 * mp + 1) * 16 * PITCH_E + ks * 32);
                    ah[2 * mp + 0][0] = __builtin_amdgcn_mfma_f32_16x16x32_bf16(a0, bv0, ah[2 * mp + 0][0], 0, 0, 0);
                    ah[2 * mp + 0][1] = __builtin_amdgcn_mfma_f32_16x16x32_bf16(a0, bv1, ah[2 * mp + 0][1], 0, 0, 0);
                    ah[2 * mp + 1][0] = __builtin_amdgcn_mfma_f32_16x16x32_bf16(a1, bv0, ah[2 * mp + 1][0], 0, 0, 0);
                    ah[2 * mp + 1][1] = __builtin_amdgcn_mfma_f32_16x16x32_bf16(a1, bv1, ah[2 * mp + 1][1], 0, 0, 0);
                }
                __builtin_amdgcn_s_setprio(0);
            }
            #pragma unroll
            for (int ct = 0; ct < 2; ++ct) {
                int col = colbase + ct * 16 + lm;
                float b = bb1[c * H_ + col];
                #pragma unroll
                for (int mt = 0; mt < 8; ++mt)
                    #pragma unroll
                    for (int g = 0; g < 4; ++g)
                        if (s_cmd[mt * 16 + kg * 4 + g] == c)
                            res[mt][ct][g] = (__bf16)fmaxf(ah[mt][ct][g] + b, 0.f);
            }
        }
    } else {
        const __bf16* bb = PK + PKO_OW1 + laneoffB;
        f32x4 ta[8][2];
        #pragma unroll
        for (int mt = 0; mt < 8; ++mt) {
            ta[mt][0] = f32x4{0.f, 0.f, 0.f, 0.f};
            ta[mt][1] = f32x4{0.f, 0.f, 0.f, 0.f};
        }
        #pragma unroll 2
        for (int ks = 0; ks < 16; ++ks) {
            bf16x8 bv0 = *(const bf16x8*)(bb + (size_t)ks * 8192);
            bf16x8 bv1 = *(const bf16x8*)(bb + (size_t)ks * 8192 + 512);
            __builtin_amdgcn_s_setprio(1);
            #pragma unroll
            for (int mp = 0; mp < 4; ++mp) {
                bf16x8 a0 = *(const bf16x8*)(aXbase + (2 * mp + 0) * 16 * PITCH_E + ks * 32);
                bf16x8 a1 = *(const bf16x8*)(aXbase + (2 * mp + 1) * 16 * PITCH_E + ks * 32);
                ta[2 * mp + 0][0] = __builtin_amdgcn_mfma_f32_16x16x32_bf16(a0, bv0, ta[2 * mp + 0][0], 0, 0, 0);
                ta[2 * mp + 0][1] = __builtin_amdgcn_mfma_f32_16x16x32_bf16(a0, bv1, ta[2 * mp + 0][1], 0, 0, 0);
                ta[2 * mp + 1][0] = __builtin_amdgcn_mfma_f32_16x16x32_bf16(a1, bv0, ta[2 * mp + 1][0], 0, 0, 0);
                ta[2 * mp + 1][1] = __builtin_amdgcn_mfma_f32_16x16x32_bf16(a1, bv1, ta[2 * mp + 1][1], 0, 0, 0);
            }
            __builtin_amdgcn_s_setprio(0);
        }
        #pragma unroll
        for (int ct = 0; ct < 2; ++ct) {
            int col = colbase + ct * 16 + lm;
            float b = ob1[col];
            #pragma unroll
            for (int mt = 0; mt < 8; ++mt)
                #pragma unroll
                for (int g = 0; g < 4; ++g)
                    res[mt][ct][g] = (__bf16)fmaxf(ta[mt][ct][g] + b, 0.f);
        }
    }
    __syncthreads();   // all emb reads complete before overwrite

    // ---- write [h1 | t1] back into s_x ----
    {
        const int colW = (roleB ? 0 : 256) + colbase;
        #pragma unroll
        for (int ct = 0; ct < 2; ++ct) {
            int col = colW + ct * 16 + lm;
            #pragma unroll
            for (int mt = 0; mt < 8; ++mt)
                #pragma unroll
                for (int g = 0; g < 4; ++g)
                    s_x[(mt * 16 + kg * 4 + g) * PITCH_E + col] = res[mt][ct][g];
        }
    }
    __syncthreads();

    // ---- phase 4: h2+control (waves 0-7) | t2+speed (waves 8-15), two row-halves ----
    const __bf16* aHbase = s_x + lm * PITCH_E + (roleB ? 0 : 256) + kg * 8;
    if (roleB) {
        for (int c = cmin; c <= cmax; ++c) {
            const __bf16* bb = PK + PKO_BW2 + (unsigned)c * 65536u + laneoffB;
            #pragma unroll
            for (int rh = 0; rh < 2; ++rh) {
                f32x4 hh[4][2];
                #pragma unroll
                for (int mt = 0; mt < 4; ++mt) {
                    hh[mt][0] = f32x4{0.f, 0.f, 0.f, 0.f};
                    hh[mt][1] = f32x4{0.f, 0.f, 0.f, 0.f};
                }
                #pragma unroll 2
                for (int ks = 0; ks < 8; ++ks) {
                    bf16x8 bv0 = *(const bf16x8*)(bb + (size_t)ks * 8192);
                    bf16x8 bv1 = *(const bf16x8*)(bb + (size_t)ks * 8192 + 512);
                    __builtin_amdgcn_s_setprio(1);
                    #pragma unroll
                    for (int mt = 0; mt < 4; ++mt) {
                        bf16x8 a = *(const bf16x8*)(aHbase + (rh * 4 + mt) * 16 * PITCH_E + ks * 32);
                        hh[mt][0] = __builtin_amdgcn_mfma_f32_16x16x32_bf16(a, bv0, hh[mt][0], 0, 0, 0);
                        hh[mt][1] = __builtin_amdgcn_mfma_f32_16x16x32_bf16(a, bv1, hh[mt][1], 0, 0, 0);
                    }
                    __builtin_amdgcn_s_setprio(0);
                }
                float ph[4][4][3];
                #pragma unroll
                for (int mt = 0; mt < 4; ++mt)
                    #pragma unroll
                    for (int g = 0; g < 4; ++g) { ph[mt][g][0] = 0.f; ph[mt][g][1] = 0.f; ph[mt][g][2] = 0.f; }
                #pragma unroll
                for (int ct = 0; ct < 2; ++ct) {
                    int col = colbase + ct * 16 + lm;
                    float b  = bb2[c * H_ + col];
                    float w0 = bw3[(c * H_ + col) * 3 + 0];
                    float w1 = bw3[(c * H_ + col) * 3 + 1];
                    float w2 = bw3[(c * H_ + col) * 3 + 2];
                    #pragma unroll
                    for (int mt = 0; mt < 4; ++mt)
                        #pragma unroll
                        for (int g = 0; g < 4; ++g) {
                            float h = fmaxf(hh[mt][ct][g] + b, 0.f);
                            ph[mt][g][0] += h * w0; ph[mt][g][1] += h * w1; ph[mt][g][2] += h * w2;
                        }
                }
                #pragma unroll
                for (int mt = 0; mt < 4; ++mt)
                    #pragma unroll
                    for (int g = 0; g < 4; ++g)
                        #pragma unroll
                        for (int o = 0; o < 3; ++o) {
                            float v = ph[mt][g][o];
                            v += __shfl_xor(v, 1); v += __shfl_xor(v, 2);
                            v += __shfl_xor(v, 4); v += __shfl_xor(v, 8);
                            ph[mt][g][o] = v;
                        }
                if (lm == 0) {
                    #pragma unroll
                    for (int mt = 0; mt < 4; ++mt)
                        #pragma unroll
                        for (int g = 0; g < 4; ++g) {
                            int row = (rh * 4 + mt) * 16 + kg * 4 + g;
                            if (s_cmd[row] == c) {
                                atomicAdd(&s_head[row][0], ph[mt][g][0]);
                                atomicAdd(&s_head[row][1], ph[mt][g][1]);
                                atomicAdd(&s_head[row][2], ph[mt][g][2]);
                            }
                        }
                }
            }
        }
    } else {
        float sp[8][4];
        #pragma unroll
        for (int mt = 0; mt < 8; ++mt)
            #pragma unroll
            for (int g = 0; g < 4; ++g) sp[mt][g] = 0.f;
        const __bf16* bb = PK + PKO_OW2 + laneoffB;
        #pragma unroll
        for (int rh = 0; rh < 2; ++rh) {
            f32x4 hh[4][2];
            #pragma unroll
            for (int mt = 0; mt < 4; ++mt) {
                hh[mt][0] = f32x4{0.f, 0.f, 0.f, 0.f};
                hh[mt][1] = f32x4{0.f, 0.f, 0.f, 0.f};
            }
            #pragma unroll 2
            for (int ks = 0; ks < 8; ++ks) {
                bf16x8 bv0 = *(const bf16x8*)(bb + (size_t)ks * 8192);
                bf16x8 bv1 = *(const bf16x8*)(bb + (size_t)ks * 8192 + 512);
                __builtin_amdgcn_s_setprio(1);
                #pragma unroll
                for (int mt = 0; mt < 4; ++mt) {
                    bf16x8 a = *(const bf16x8*)(aHbase + (rh * 4 + mt) * 16 * PITCH_E + ks * 32);
                    hh[mt][0] = __builtin_amdgcn_mfma_f32_16x16x32_bf16(a, bv0, hh[mt][0], 0, 0, 0);
                    hh[mt][1] = __builtin_amdgcn_mfma_f32_16x16x32_bf16(a, bv1, hh[mt][1], 0, 0, 0);
                }
                __builtin_amdgcn_s_setprio(0);
            }
            #pragma unroll
            for (int ct = 0; ct < 2; ++ct) {
                int col = colbase + ct * 16 + lm;
                float b = ob2[col], wv = ow3[col];
                #pragma unroll
                for (int mt = 0; mt < 4; ++mt)
                    #pragma unroll
                    for (int g = 0; g < 4; ++g)
                        sp[rh * 4 + mt][g] += fmaxf(hh[mt][ct][g] + b, 0.f) * wv;
            }
        }
        #pragma unroll
        for (int mt = 0; mt < 8; ++mt)
            #pragma unroll
            for (int g = 0; g < 4; ++g) {
                float v = sp[mt][g];
                v += __shfl_xor(v, 1); v += __shfl_xor(v, 2);
                v += __shfl_xor(v, 4); v += __shfl_xor(v, 8);
                if (lm == 0) atomicAdd(&s_head[mt * 16 + kg * 4 + g][3], v);
            }
    }
    __syncthreads();

    if (tid < 128) {
        int r = s_row[tid], c = s_cmd[tid];
        #pragma unroll
        for (int o = 0; o < 3; ++o) {
            float x = s_head[tid][o] + bb3[c * 3 + o];
            __builtin_nontemporal_store(1.f / (1.f + __expf(-x)), &out[(size_t)r * 3 + o]);
        }
        __builtin_nontemporal_store(s_head[tid][3] + ob3[0], &out[(size_t)3 * B_ + r]);
    }
}

// ---------------- fallback (fp32, no ws) ----------------

__global__ __launch_bounds__(256) void cilrs_slow(
    const float* __restrict__ embedding, const float* __restrict__ speed,
    const int* __restrict__ command,
    const float* __restrict__ sw1, const float* __restrict__ sb1,
    const float* __restrict__ sw2, const float* __restrict__ sb2,
    const float* __restrict__ bw1, const float* __restrict__ bb1,
    const float* __restrict__ bw2, const float* __restrict__ bb2,
    const float* __restrict__ bw3, const float* __restrict__ bb3,
    const float* __restrict__ ow1, const float* __restrict__ ob1,
    const float* __restrict__ ow2, const float* __restrict__ ob2,
    const float* __restrict__ ow3, const float* __restrict__ ob3,
    float* __restrict__ out)
{
    const int row = blockIdx.x;
    const int j   = threadIdx.x;
    __shared__ float sh[H_];
    __shared__ float emb[D_];
    __shared__ float h1[H_];
    __shared__ float h2[H_];
    const float spd = speed[row];
    { float v = spd * sw1[j] + sb1[j]; sh[j] = v > 0.f ? v : 0.f; }
    __syncthreads();
    {
        float a0 = 0.f, a1 = 0.f;
        for (int h = 0; h < H_; ++h) {
            const float s = sh[h];
            a0 += s * sw2[h * D_ + j];
            a1 += s * sw2[h * D_ + j + 256];
        }
        emb[j]       = embedding[(size_t)row * D_ + j]       + a0 + sb2[j];
        emb[j + 256] = embedding[(size_t)row * D_ + j + 256] + a1 + sb2[j + 256];
    }
    __syncthreads();
    const int n = command[row] - 1;
    {
        const float* wp = bw1 + (size_t)n * D_ * H_;
        float a = 0.f;
        for (int d = 0; d < D_; ++d) a += emb[d] * wp[d * H_ + j];
        a += bb1[n * H_ + j];
        h1[j] = a > 0.f ? a : 0.f;
    }
    __syncthreads();
    {
        const float* wp = bw2 + (size_t)n * H_ * H_;
        float a = 0.f;
        for (int h = 0; h < H_; ++h) a += h1[h] * wp[h * H_ + j];
        a += bb2[n * H_ + j];
        h2[j] = a > 0.f ? a : 0.f;
    }
    __syncthreads();
    {
        float a = 0.f;
        for (int d = 0; d < D_; ++d) a += emb[d] * ow1[d * H_ + j];
        a += ob1[j];
        sh[j] = a > 0.f ? a : 0.f;
    }
    __syncthreads();
    {
        float a = 0.f;
        for (int h = 0; h < H_; ++h) a += sh[h] * ow2[h * H_ + j];
        a += ob2[j];
        h1[j] = a > 0.f ? a : 0.f;
    }
    __syncthreads();
    if (j < 3) {
        const float* wp = bw3 + (size_t)n * H_ * 3;
        float a = 0.f;
        for (int h = 0; h < H_; ++h) a += h2[h] * wp[h * 3 + j];
        a += bb3[n * 3 + j];
        out[(size_t)row * 3 + j] = 1.f / (1.f + expf(-a));
    } else if (j == 3) {
        float a = 0.f;
        for (int h = 0; h < H_; ++h) a += h1[h] * ow3[h];
        a += ob3[0];
        out[(size_t)B_ * 3 + row] = a;
    }
}

// ---------------- launch ----------------

extern "C" void kernel_launch(void* const* d_in, const int* in_sizes, int n_in,
                              void* d_out, int out_size, void* d_ws, size_t ws_size,
                              hipStream_t stream) {
    const float* embedding = (const float*)d_in[0];
    const float* speed     = (const float*)d_in[1];
    const int*   command   = (const int*)  d_in[2];
    const float* sw1 = (const float*)d_in[3];
    const float* sb1 = (const float*)d_in[4];
    const float* sw2 = (const float*)d_in[5];
    const float* sb2 = (const float*)d_in[6];
    const float* bw1 = (const float*)d_in[7];
    const float* bb1 = (const float*)d_in[8];
    const float* bw2 = (const float*)d_in[9];
    const float* bb2 = (const float*)d_in[10];
    const float* bw3 = (const float*)d_in[11];
    const float* bb3 = (const float*)d_in[12];
    const float* ow1 = (const float*)d_in[13];
    const float* ob1 = (const float*)d_in[14];
    const float* ow2 = (const float*)d_in[15];
    const float* ob2 = (const float*)d_in[16];
    const float* ow3 = (const float*)d_in[17];
    const float* ob3 = (const float*)d_in[18];
    float* out = (float*)d_out;

    if (ws_size < (size_t)WS_NEEDED) {
        cilrs_slow<<<B_, 256, 0, stream>>>(embedding, speed, command,
                                           sw1, sb1, sw2, sb2,
                                           bw1, bb1, bw2, bb2, bw3, bb3,
                                           ow1, ob1, ow2, ob2, ow3, ob3, out);
        return;
    }

    char* ws = (char*)d_ws;
    int*    counts  = (int*)    ws;          // [0..23]
    int*    cursor2 = (int*)   (ws + 24);    // [24..47]
    int*    perm    = (int*)   (ws + OFF_PERM);
    __bf16* PK      = (__bf16*)(ws + OFF_PACK);

    hipMemsetAsync(ws, 0, 64, stream);
    k_count<<<64, 256, 0, stream>>>(command, counts);
    k_prepB<<<992, 256, 0, stream>>>(command, counts, cursor2, perm,
                                     sw2, bw1, bw2, ow1, ow2, PK);
    k_fused<<<B_ / 128, 1024, 0, stream>>>(embedding, speed, command,
                                           sw1, sb1, sb2,
                                           bb1, bb2, bw3, bb3,
                                           ob1, ob2, ow3, ob3,
                                           perm, PK, out);
}

// Round 7
// 355.175 us; speedup vs baseline: 1.0537x; 1.0537x over previous
//
#include <hip/hip_runtime.h>
#include <math.h>

// CILRS fused head — round 14.
//  Base = round 12 (164 µs k_fused; r13's 128-row variant regressed -> reverted).
//  New: staging/compute overlap — stage iters 0-7, then the ENTIRE phase-1
//  (speedMLP) MFMA K-loop (touches no LDS), then stage iters 8-15, then the
//  barrier + RMW epilogue. Hides ~half the per-block staging behind compute.
//  Keep: 64-row/512-thread/2-blk-per-CU geometry, NT emb loads, unroll 4,
//  setprio around MFMA, parallel k_count, NT out stores.

#define B_ 65536
#define D_ 512
#define H_ 256

typedef float  f32x4   __attribute__((ext_vector_type(4)));
typedef __bf16 bf16x8  __attribute__((ext_vector_type(8)));
typedef __bf16 bf16x4  __attribute__((ext_vector_type(4)));
typedef float  float4v __attribute__((ext_vector_type(4)));

// ---- ws layout (bytes) ----
// [0..23]  counts[6]   (zeroed by hipMemsetAsync)
// [24..47] cursor2[6]  (zeroed by hipMemsetAsync)
#define OFF_PERM     256        // 65536 ints
#define OFF_PACK     262400     // packed bf16 weights (3,014,656 B)
#define WS_NEEDED    3277056

// packed element offsets (bf16 elements, relative to PK); layout [kc][n][32k]
#define PKO_SW2   0u
#define PKO_BW1   131072u
#define PKO_BW2   917504u
#define PKO_OW1   1310720u
#define PKO_OW2   1441792u

#define PITCH_E 520   // row pitch (bf16) for the 64x512 tile

// ---------------- prep 1: 64-block histogram ----------------

__global__ __launch_bounds__(256) void k_count(const int* __restrict__ command,
                                               int* __restrict__ counts) {
    __shared__ int lh[6];
    int t = threadIdx.x;
    if (t < 6) lh[t] = 0;
    __syncthreads();
    int i = blockIdx.x * 256 + t;
    int4 v = ((const int4*)command)[i];
    int a[4] = {v.x, v.y, v.z, v.w};
    #pragma unroll
    for (int j = 0; j < 4; ++j) {
        int c = min(max(a[j] - 1, 0), 5);
        atomicAdd(&lh[c], 1);
    }
    __syncthreads();
    if (t < 6) atomicAdd(&counts[t], lh[t]);
}

// ---------------- prep 2: scatter + pack fused ----------------

__global__ __launch_bounds__(256) void k_prepB(const int* __restrict__ command,
                                               const int* __restrict__ counts,
                                               int* __restrict__ cursor2,
                                               int* __restrict__ perm,
                                               const float* __restrict__ sw2,
                                               const float* __restrict__ bw1,
                                               const float* __restrict__ bw2,
                                               const float* __restrict__ ow1,
                                               const float* __restrict__ ow2,
                                               __bf16* __restrict__ PK) {
    int t = threadIdx.x;
    if (blockIdx.x < 256) {
        // ---- scatter ----
        __shared__ int lh[6], lbase[6];
        if (t < 6) lh[t] = 0;
        __syncthreads();
        int i = blockIdx.x * 256 + t;
        int c = command[i] - 1; c = min(max(c, 0), 5);
        int rank = atomicAdd(&lh[c], 1);
        __syncthreads();
        if (t < 6) {
            int base = 0;
            #pragma unroll
            for (int k = 0; k < 6; ++k) base += (k < t) ? counts[k] : 0;
            lbase[t] = base + atomicAdd(&cursor2[t], lh[t]);
        }
        __syncthreads();
        perm[lbase[c] + rank] = i;
        return;
    }
    // ---- pack: W [C][K][N] fp32 -> PK bf16 [kc][n][32k] ----
    int b = blockIdx.x - 256;
    const float* src; int srcN, colOff; unsigned dstOff; int tt;
    if (b < 64)       { int s = b >> 5;        tt = b & 31;  src = sw2;                          srcN = 512; colOff = s * 256; dstOff = PKO_SW2 + s * 65536u; }
    else if (b < 448) { int i = b - 64;  int c = i >> 6; tt = i & 63; src = bw1 + (size_t)c * 512 * 256; srcN = 256; colOff = 0; dstOff = PKO_BW1 + c * 131072u; }
    else if (b < 640) { int i = b - 448; int c = i >> 5; tt = i & 31; src = bw2 + (size_t)c * 256 * 256; srcN = 256; colOff = 0; dstOff = PKO_BW2 + c * 65536u; }
    else if (b < 704) { tt = b - 640; src = ow1; srcN = 256; colOff = 0; dstOff = PKO_OW1; }
    else              { tt = b - 704; src = ow2; srcN = 256; colOff = 0; dstOff = PKO_OW2; }
    int kc = tt >> 2, nt = tt & 3;
    int k0 = kc * 32, n0 = nt * 64;

    __shared__ __bf16 T[64][34];
    #pragma unroll
    for (int p = 0; p < 2; ++p) {
        int idx = p * 256 + t;            // 512 chunks: 32 k x 16 n4
        int k = idx >> 4, n4 = idx & 15;
        float4v v = *(const float4v*)(src + (size_t)(k0 + k) * srcN + colOff + n0 + n4 * 4);
        T[n4 * 4 + 0][k] = (__bf16)v[0];
        T[n4 * 4 + 1][k] = (__bf16)v[1];
        T[n4 * 4 + 2][k] = (__bf16)v[2];
        T[n4 * 4 + 3][k] = (__bf16)v[3];
    }
    __syncthreads();
    int n = t >> 2, seg = t & 3;
    bf16x8 v;
    #pragma unroll
    for (int j = 0; j < 8; ++j) v[j] = T[n][seg * 8 + j];
    *(bf16x8*)(PK + dstOff + ((unsigned)(kc * 256 + n0 + n) * 32u + seg * 8u)) = v;
}

// ---------------- fused main: 64 rows/block, 8 waves, single 64x512 LDS buffer ----------------

__global__ __launch_bounds__(512, 4) void k_fused(
    const float* __restrict__ embedding, const float* __restrict__ speed,
    const int*   __restrict__ command,
    const float* __restrict__ sw1, const float* __restrict__ sb1,
    const float* __restrict__ sb2,
    const float* __restrict__ bb1, const float* __restrict__ bb2,
    const float* __restrict__ bw3, const float* __restrict__ bb3,
    const float* __restrict__ ob1, const float* __restrict__ ob2,
    const float* __restrict__ ow3, const float* __restrict__ ob3,
    const int* __restrict__ perm, const __bf16* __restrict__ PK,
    float* __restrict__ out)
{
    __shared__ __bf16 s_x[64 * PITCH_E];     // 66.6 KB: emb, then [h1|t1]
    __shared__ float  s_head[64][4];
    __shared__ int    s_row[64];
    __shared__ int    s_cmd[64];
    __shared__ float  s_spd[64];

    const int tid = threadIdx.x;
    const int w = tid >> 6, lane = tid & 63;
    const int lm = lane & 15, kg = lane >> 4;
    const int R0 = blockIdx.x * 64;

    if (tid < 64) {
        int r = perm[R0 + tid];
        s_row[tid] = r;
        int c = command[r] - 1; c = min(max(c, 0), 5);
        s_cmd[tid] = c;
        s_spd[tid] = speed[r];
        s_head[tid][0] = 0.f; s_head[tid][1] = 0.f; s_head[tid][2] = 0.f; s_head[tid][3] = 0.f;
    }
    __syncthreads();

    // ---- stage embedding half 1 (iters 0-7) ----
    #pragma unroll
    for (int it = 0; it < 8; ++it) {
        int idx = it * 512 + tid;
        int row = idx >> 7, c4 = idx & 127;
        float4v v = __builtin_nontemporal_load(
            (const float4v*)(embedding + (size_t)s_row[row] * D_ + c4 * 4));
        bf16x4 pv;
        pv[0] = (__bf16)v[0]; pv[1] = (__bf16)v[1];
        pv[2] = (__bf16)v[2]; pv[3] = (__bf16)v[3];
        *(bf16x4*)(s_x + row * PITCH_E + c4 * 4) = pv;
    }

    // ---- phase 1 COMPUTE (speedMLP, no LDS access): overlaps staging ----
    const unsigned slice = (unsigned)(w >> 2) * 65536u;
    const int mbase = (w & 3) * 64;
    f32x4 dacc[4][4];
    {
        float spd[4];
        #pragma unroll
        for (int nt = 0; nt < 4; ++nt) spd[nt] = s_spd[nt * 16 + lm];
        #pragma unroll
        for (int mt = 0; mt < 4; ++mt)
            #pragma unroll
            for (int nt = 0; nt < 4; ++nt) dacc[mt][nt] = f32x4{0.f, 0.f, 0.f, 0.f};
        #pragma unroll 4
        for (int ks = 0; ks < 8; ++ks) {
            const int k0 = ks * 32 + kg * 8;
            float4v w0 = *(const float4v*)(sw1 + k0);
            float4v w1 = *(const float4v*)(sw1 + k0 + 4);
            float4v c0 = *(const float4v*)(sb1 + k0);
            float4v c1 = *(const float4v*)(sb1 + k0 + 4);
            bf16x8 bns[4];
            #pragma unroll
            for (int nt = 0; nt < 4; ++nt)
                #pragma unroll
                for (int j = 0; j < 4; ++j) {
                    bns[nt][j]     = (__bf16)fmaxf(spd[nt] * w0[j] + c0[j], 0.f);
                    bns[nt][j + 4] = (__bf16)fmaxf(spd[nt] * w1[j] + c1[j], 0.f);
                }
            const __bf16* ap = PK + PKO_SW2 + slice + (size_t)ks * 8192
                             + (size_t)(mbase + lm) * 32 + kg * 8;
            __builtin_amdgcn_s_setprio(1);
            #pragma unroll
            for (int mt = 0; mt < 4; ++mt) {
                bf16x8 av = *(const bf16x8*)(ap + mt * 512);
                #pragma unroll
                for (int nt = 0; nt < 4; ++nt)
                    dacc[mt][nt] = __builtin_amdgcn_mfma_f32_16x16x32_bf16(av, bns[nt], dacc[mt][nt], 0, 0, 0);
            }
            __builtin_amdgcn_s_setprio(0);
        }
    }

    // ---- stage embedding half 2 (iters 8-15) ----
    #pragma unroll
    for (int it = 8; it < 16; ++it) {
        int idx = it * 512 + tid;
        int row = idx >> 7, c4 = idx & 127;
        float4v v = __builtin_nontemporal_load(
            (const float4v*)(embedding + (size_t)s_row[row] * D_ + c4 * 4));
        bf16x4 pv;
        pv[0] = (__bf16)v[0]; pv[1] = (__bf16)v[1];
        pv[2] = (__bf16)v[2]; pv[3] = (__bf16)v[3];
        *(bf16x4*)(s_x + row * PITCH_E + c4 * 4) = pv;
    }
    __syncthreads();

    const int cmin = s_cmd[0], cmax = s_cmd[63];   // perm is bucket-sorted

    // ---- phase 1 RMW epilogue: s_x += deltaT + sb2 (needs full staging) ----
    {
        #pragma unroll
        for (int mt = 0; mt < 4; ++mt) {
            int colb = w * 64 + mt * 16 + kg * 4;
            float4v sbv = *(const float4v*)(sb2 + colb);
            #pragma unroll
            for (int nt = 0; nt < 4; ++nt) {
                int row = nt * 16 + lm;
                bf16x4* p = (bf16x4*)(s_x + row * PITCH_E + colb);
                bf16x4 old = *p;
                bf16x4 nv;
                #pragma unroll
                for (int g = 0; g < 4; ++g)
                    nv[g] = (__bf16)(dacc[mt][nt][g] + sbv[g] + (float)old[g]);
                *p = nv;
            }
        }
    }
    __syncthreads();

    const bool roleB = (w < 4);
    const int colbase = (w & 3) * 64;
    const unsigned laneoffB = (unsigned)(colbase + lm) * 32u + kg * 8u;
    const __bf16* aXbase = s_x + lm * PITCH_E + kg * 8;   // + mt*16*PITCH_E

    // ---- phase 3: h1 (waves 0-3, c-loop) | t1 (waves 4-7); results in regs ----
    bf16x4 res[4][4];   // [mt][ct]
    if (roleB) {
        for (int c = cmin; c <= cmax; ++c) {
            const __bf16* bb = PK + PKO_BW1 + (unsigned)c * 131072u + laneoffB;
            f32x4 ah[4][4];
            #pragma unroll
            for (int mt = 0; mt < 4; ++mt)
                #pragma unroll
                for (int ct = 0; ct < 4; ++ct) ah[mt][ct] = f32x4{0.f, 0.f, 0.f, 0.f};
            #pragma unroll 4
            for (int ks = 0; ks < 16; ++ks) {
                bf16x8 a[4];
                #pragma unroll
                for (int mt = 0; mt < 4; ++mt)
                    a[mt] = *(const bf16x8*)(aXbase + mt * 16 * PITCH_E + ks * 32);
                __builtin_amdgcn_s_setprio(1);
                #pragma unroll
                for (int ct = 0; ct < 4; ++ct) {
                    bf16x8 bv = *(const bf16x8*)(bb + (size_t)ks * 8192 + ct * 512);
                    #pragma unroll
                    for (int mt = 0; mt < 4; ++mt)
                        ah[mt][ct] = __builtin_amdgcn_mfma_f32_16x16x32_bf16(a[mt], bv, ah[mt][ct], 0, 0, 0);
                }
                __builtin_amdgcn_s_setprio(0);
            }
            #pragma unroll
            for (int ct = 0; ct < 4; ++ct) {
                int col = colbase + ct * 16 + lm;
                float b = bb1[c * H_ + col];
                #pragma unroll
                for (int mt = 0; mt < 4; ++mt)
                    #pragma unroll
                    for (int g = 0; g < 4; ++g)
                        if (s_cmd[mt * 16 + kg * 4 + g] == c)
                            res[mt][ct][g] = (__bf16)fmaxf(ah[mt][ct][g] + b, 0.f);
            }
        }
    } else {
        const __bf16* bb = PK + PKO_OW1 + laneoffB;
        f32x4 ta[4][4];
        #pragma unroll
        for (int mt = 0; mt < 4; ++mt)
            #pragma unroll
            for (int ct = 0; ct < 4; ++ct) ta[mt][ct] = f32x4{0.f, 0.f, 0.f, 0.f};
        #pragma unroll 4
        for (int ks = 0; ks < 16; ++ks) {
            bf16x8 a[4];
            #pragma unroll
            for (int mt = 0; mt < 4; ++mt)
                a[mt] = *(const bf16x8*)(aXbase + mt * 16 * PITCH_E + ks * 32);
            __builtin_amdgcn_s_setprio(1);
            #pragma unroll
            for (int ct = 0; ct < 4; ++ct) {
                bf16x8 bv = *(const bf16x8*)(bb + (size_t)ks * 8192 + ct * 512);
                #pragma unroll
                for (int mt = 0; mt < 4; ++mt)
                    ta[mt][ct] = __builtin_amdgcn_mfma_f32_16x16x32_bf16(a[mt], bv, ta[mt][ct], 0, 0, 0);
            }
            __builtin_amdgcn_s_setprio(0);
        }
        #pragma unroll
        for (int ct = 0; ct < 4; ++ct) {
            int col = colbase + ct * 16 + lm;
            float b = ob1[col];
            #pragma unroll
            for (int mt = 0; mt < 4; ++mt)
                #pragma unroll
                for (int g = 0; g < 4; ++g)
                    res[mt][ct][g] = (__bf16)fmaxf(ta[mt][ct][g] + b, 0.f);
        }
    }
    __syncthreads();   // all emb reads complete before overwrite

    // ---- write [h1 | t1] back into s_x ----
    {
        const int colW = (roleB ? 0 : 256) + colbase;
        #pragma unroll
        for (int ct = 0; ct < 4; ++ct) {
            int col = colW + ct * 16 + lm;
            #pragma unroll
            for (int mt = 0; mt < 4; ++mt)
                #pragma unroll
                for (int g = 0; g < 4; ++g)
                    s_x[(mt * 16 + kg * 4 + g) * PITCH_E + col] = res[mt][ct][g];
        }
    }
    __syncthreads();

    // ---- phase 4: h2+control (waves 0-3) | t2+speed (waves 4-7), two row-halves ----
    const __bf16* aHbase = s_x + lm * PITCH_E + (roleB ? 0 : 256) + kg * 8;
    if (roleB) {
        for (int c = cmin; c <= cmax; ++c) {
            const __bf16* bb = PK + PKO_BW2 + (unsigned)c * 65536u + laneoffB;
            #pragma unroll
            for (int rh = 0; rh < 2; ++rh) {
                f32x4 hh[2][4];
                #pragma unroll
                for (int mt = 0; mt < 2; ++mt)
                    #pragma unroll
                    for (int ct = 0; ct < 4; ++ct) hh[mt][ct] = f32x4{0.f, 0.f, 0.f, 0.f};
                #pragma unroll 4
                for (int ks = 0; ks < 8; ++ks) {
                    bf16x8 a0 = *(const bf16x8*)(aHbase + (rh * 2 + 0) * 16 * PITCH_E + ks * 32);
                    bf16x8 a1 = *(const bf16x8*)(aHbase + (rh * 2 + 1) * 16 * PITCH_E + ks * 32);
                    __builtin_amdgcn_s_setprio(1);
                    #pragma unroll
                    for (int ct = 0; ct < 4; ++ct) {
                        bf16x8 bv = *(const bf16x8*)(bb + (size_t)ks * 8192 + ct * 512);
                        hh[0][ct] = __builtin_amdgcn_mfma_f32_16x16x32_bf16(a0, bv, hh[0][ct], 0, 0, 0);
                        hh[1][ct] = __builtin_amdgcn_mfma_f32_16x16x32_bf16(a1, bv, hh[1][ct], 0, 0, 0);
                    }
                    __builtin_amdgcn_s_setprio(0);
                }
                float ph[2][4][3];
                #pragma unroll
                for (int mt = 0; mt < 2; ++mt)
                    #pragma unroll
                    for (int g = 0; g < 4; ++g) { ph[mt][g][0] = 0.f; ph[mt][g][1] = 0.f; ph[mt][g][2] = 0.f; }
                #pragma unroll
                for (int ct = 0; ct < 4; ++ct) {
                    int col = colbase + ct * 16 + lm;
                    float b  = bb2[c * H_ + col];
                    float w0 = bw3[(c * H_ + col) * 3 + 0];
                    float w1 = bw3[(c * H_ + col) * 3 + 1];
                    float w2 = bw3[(c * H_ + col) * 3 + 2];
                    #pragma unroll
                    for (int mt = 0; mt < 2; ++mt)
                        #pragma unroll
                        for (int g = 0; g < 4; ++g) {
                            float h = fmaxf(hh[mt][ct][g] + b, 0.f);
                            ph[mt][g][0] += h * w0; ph[mt][g][1] += h * w1; ph[mt][g][2] += h * w2;
                        }
                }
                #pragma unroll
                for (int mt = 0; mt < 2; ++mt)
                    #pragma unroll
                    for (int g = 0; g < 4; ++g)
                        #pragma unroll
                        for (int o = 0; o < 3; ++o) {
                            float v = ph[mt][g][o];
                            v += __shfl_xor(v, 1); v += __shfl_xor(v, 2);
                            v += __shfl_xor(v, 4); v += __shfl_xor(v, 8);
                            ph[mt][g][o] = v;
                        }
                if (lm == 0) {
                    #pragma unroll
                    for (int mt = 0; mt < 2; ++mt)
                        #pragma unroll
                        for (int g = 0; g < 4; ++g) {
                            int row = (rh * 2 + mt) * 16 + kg * 4 + g;
                            if (s_cmd[row] == c) {
                                atomicAdd(&s_head[row][0], ph[mt][g][0]);
                                atomicAdd(&s_head[row][1], ph[mt][g][1]);
                                atomicAdd(&s_head[row][2], ph[mt][g][2]);
                            }
                        }
                }
            }
        }
    } else {
        float sp[4][4];
        #pragma unroll
        for (int mt = 0; mt < 4; ++mt)
            #pragma unroll
            for (int g = 0; g < 4; ++g) sp[mt][g] = 0.f;
        const __bf16* bb = PK + PKO_OW2 + laneoffB;
        #pragma unroll
        for (int rh = 0; rh < 2; ++rh) {
            f32x4 hh[2][4];
            #pragma unroll
            for (int mt = 0; mt < 2; ++mt)
                #pragma unroll
                for (int ct = 0; ct < 4; ++ct) hh[mt][ct] = f32x4{0.f, 0.f, 0.f, 0.f};
            #pragma unroll 4
            for (int ks = 0; ks < 8; ++ks) {
                bf16x8 a0 = *(const bf16x8*)(aHbase + (rh * 2 + 0) * 16 * PITCH_E + ks * 32);
                bf16x8 a1 = *(const bf16x8*)(aHbase + (rh * 2 + 1) * 16 * PITCH_E + ks * 32);
                __builtin_amdgcn_s_setprio(1);
                #pragma unroll
                for (int ct = 0; ct < 4; ++ct) {
                    bf16x8 bv = *(const bf16x8*)(bb + (size_t)ks * 8192 + ct * 512);
                    hh[0][ct] = __builtin_amdgcn_mfma_f32_16x16x32_bf16(a0, bv, hh[0][ct], 0, 0, 0);
                    hh[1][ct] = __builtin_amdgcn_mfma_f32_16x16x32_bf16(a1, bv, hh[1][ct], 0, 0, 0);
                }
                __builtin_amdgcn_s_setprio(0);
            }
            #pragma unroll
            for (int ct = 0; ct < 4; ++ct) {
                int col = colbase + ct * 16 + lm;
                float b = ob2[col], wv = ow3[col];
                #pragma unroll
                for (int mt = 0; mt < 2; ++mt)
                    #pragma unroll
                    for (int g = 0; g < 4; ++g)
                        sp[rh * 2 + mt][g] += fmaxf(hh[mt][ct][g] + b, 0.f) * wv;
            }
        }
        #pragma unroll
        for (int mt = 0; mt < 4; ++mt)
            #pragma unroll
            for (int g = 0; g < 4; ++g) {
                float v = sp[mt][g];
                v += __shfl_xor(v, 1); v += __shfl_xor(v, 2);
                v += __shfl_xor(v, 4); v += __shfl_xor(v, 8);
                if (lm == 0) atomicAdd(&s_head[mt * 16 + kg * 4 + g][3], v);
            }
    }
    __syncthreads();

    if (tid < 64) {
        int r = s_row[tid], c = s_cmd[tid];
        #pragma unroll
        for (int o = 0; o < 3; ++o) {
            float x = s_head[tid][o] + bb3[c * 3 + o];
            __builtin_nontemporal_store(1.f / (1.f + __expf(-x)), &out[(size_t)r * 3 + o]);
        }
        __builtin_nontemporal_store(s_head[tid][3] + ob3[0], &out[(size_t)3 * B_ + r]);
    }
}

// ---------------- fallback (fp32, no ws) ----------------

__global__ __launch_bounds__(256) void cilrs_slow(
    const float* __restrict__ embedding, const float* __restrict__ speed,
    const int* __restrict__ command,
    const float* __restrict__ sw1, const float* __restrict__ sb1,
    const float* __restrict__ sw2, const float* __restrict__ sb2,
    const float* __restrict__ bw1, const float* __restrict__ bb1,
    const float* __restrict__ bw2, const float* __restrict__ bb2,
    const float* __restrict__ bw3, const float* __restrict__ bb3,
    const float* __restrict__ ow1, const float* __restrict__ ob1,
    const float* __restrict__ ow2, const float* __restrict__ ob2,
    const float* __restrict__ ow3, const float* __restrict__ ob3,
    float* __restrict__ out)
{
    const int row = blockIdx.x;
    const int j   = threadIdx.x;
    __shared__ float sh[H_];
    __shared__ float emb[D_];
    __shared__ float h1[H_];
    __shared__ float h2[H_];
    const float spd = speed[row];
    { float v = spd * sw1[j] + sb1[j]; sh[j] = v > 0.f ? v : 0.f; }
    __syncthreads();
    {
        float a0 = 0.f, a1 = 0.f;
        for (int h = 0; h < H_; ++h) {
            const float s = sh[h];
            a0 += s * sw2[h * D_ + j];
            a1 += s * sw2[h * D_ + j + 256];
        }
        emb[j]       = embedding[(size_t)row * D_ + j]       + a0 + sb2[j];
        emb[j + 256] = embedding[(size_t)row * D_ + j + 256] + a1 + sb2[j + 256];
    }
    __syncthreads();
    const int n = command[row] - 1;
    {
        const float* wp = bw1 + (size_t)n * D_ * H_;
        float a = 0.f;
        for (int d = 0; d < D_; ++d) a += emb[d] * wp[d * H_ + j];
        a += bb1[n * H_ + j];
        h1[j] = a > 0.f ? a : 0.f;
    }
    __syncthreads();
    {
        const float* wp = bw2 + (size_t)n * H_ * H_;
        float a = 0.f;
        for (int h = 0; h < H_; ++h) a += h1[h] * wp[h * H_ + j];
        a += bb2[n * H_ + j];
        h2[j] = a > 0.f ? a : 0.f;
    }
    __syncthreads();
    {
        float a = 0.f;
        for (int d = 0; d < D_; ++d) a += emb[d] * ow1[d * H_ + j];
        a += ob1[j];
        sh[j] = a > 0.f ? a : 0.f;
    }
    __syncthreads();
    {
        float a = 0.f;
        for (int h = 0; h < H_; ++h) a += sh[h] * ow2[h * H_ + j];
        a += ob2[j];
        h1[j] = a > 0.f ? a : 0.f;
    }
    __syncthreads();
    if (j < 3) {
        const float* wp = bw3 + (size_t)n * H_ * 3;
        float a = 0.f;
        for (int h = 0; h < H_; ++h) a += h2[h] * wp[h * 3 + j];
        a += bb3[n * 3 + j];
        out[(size_t)row * 3 + j] = 1.f / (1.f + expf(-a));
    } else if (j == 3) {
        float a = 0.f;
        for (int h = 0; h < H_; ++h) a += h1[h] * ow3[h];
        a += ob3[0];
        out[(size_t)B_ * 3 + row] = a;
    }
}

// ---------------- launch ----------------

extern "C" void kernel_launch(void* const* d_in, const int* in_sizes, int n_in,
                              void* d_out, int out_size, void* d_ws, size_t ws_size,
                              hipStream_t stream) {
    const float* embedding = (const float*)d_in[0];
    const float* speed     = (const float*)d_in[1];
    const int*   command   = (const int*)  d_in[2];
    const float* sw1 = (const float*)d_in[3];
    const float* sb1 = (const float*)d_in[4];
    const float* sw2 = (const float*)d_in[5];
    const float* sb2 = (const float*)d_in[6];
    const float* bw1 = (const float*)d_in[7];
    const float* bb1 = (const float*)d_in[8];
    const float* bw2 = (const float*)d_in[9];
    const float* bb2 = (const float*)d_in[10];
    const float* bw3 = (const float*)d_in[11];
    const float* bb3 = (const float*)d_in[12];
    const float* ow1 = (const float*)d_in[13];
    const float* ob1 = (const float*)d_in[14];
    const float* ow2 = (const float*)d_in[15];
    const float* ob2 = (const float*)d_in[16];
    const float* ow3 = (const float*)d_in[17];
    const float* ob3 = (const float*)d_in[18];
    float* out = (float*)d_out;

    if (ws_size < (size_t)WS_NEEDED) {
        cilrs_slow<<<B_, 256, 0, stream>>>(embedding, speed, command,
                                           sw1, sb1, sw2, sb2,
                                           bw1, bb1, bw2, bb2, bw3, bb3,
                                           ow1, ob1, ow2, ob2, ow3, ob3, out);
        return;
    }

    char* ws = (char*)d_ws;
    int*    counts  = (int*)    ws;          // [0..23]
    int*    cursor2 = (int*)   (ws + 24);    // [24..47]
    int*    perm    = (int*)   (ws + OFF_PERM);
    __bf16* PK      = (__bf16*)(ws + OFF_PACK);

    hipMemsetAsync(ws, 0, 64, stream);
    k_count<<<64, 256, 0, stream>>>(command, counts);
    k_prepB<<<992, 256, 0, stream>>>(command, counts, cursor2, perm,
                                     sw2, bw1, bw2, ow1, ow2, PK);
    k_fused<<<B_ / 64, 512, 0, stream>>>(embedding, speed, command,
                                         sw1, sb1, sb2,
                                         bb1, bb2, bw3, bb3,
                                         ob1, ob2, ow3, ob3,
                                         perm, PK, out);
}

// Round 8
// 351.813 us; speedup vs baseline: 1.0637x; 1.0096x over previous
//
#include <hip/hip_runtime.h>
#include <math.h>

// CILRS fused head — round 15.
//  Base = round 12 exactly (164 µs k_fused; r13 tile and r14 overlap both
//  regressed and are reverted). One new lever: XCD-aware block swizzle.
//  perm is command-sorted; blocks round-robin across 8 XCDs, so every XCD
//  previously touched ALL commands' weights (3 MB PK vs 4 MB L2, thrashed by
//  the 134 MB NT embedding stream -> L3-latency B-loads). Remap
//  orig = (bid%8)*128 + bid/8 so each XCD gets a contiguous 128-block range
//  (1-2 commands, ~1 MB weights) -> L2-resident B-operands.

#define B_ 65536
#define D_ 512
#define H_ 256

typedef float  f32x4   __attribute__((ext_vector_type(4)));
typedef __bf16 bf16x8  __attribute__((ext_vector_type(8)));
typedef __bf16 bf16x4  __attribute__((ext_vector_type(4)));
typedef float  float4v __attribute__((ext_vector_type(4)));

// ---- ws layout (bytes) ----
// [0..23]  counts[6]   (zeroed by hipMemsetAsync)
// [24..47] cursor2[6]  (zeroed by hipMemsetAsync)
#define OFF_PERM     256        // 65536 ints
#define OFF_PACK     262400     // packed bf16 weights (3,014,656 B)
#define WS_NEEDED    3277056

// packed element offsets (bf16 elements, relative to PK); layout [kc][n][32k]
#define PKO_SW2   0u
#define PKO_BW1   131072u
#define PKO_BW2   917504u
#define PKO_OW1   1310720u
#define PKO_OW2   1441792u

#define PITCH_E 520   // row pitch (bf16) for the 64x512 tile

// ---------------- prep 1: 64-block histogram ----------------

__global__ __launch_bounds__(256) void k_count(const int* __restrict__ command,
                                               int* __restrict__ counts) {
    __shared__ int lh[6];
    int t = threadIdx.x;
    if (t < 6) lh[t] = 0;
    __syncthreads();
    int i = blockIdx.x * 256 + t;
    int4 v = ((const int4*)command)[i];
    int a[4] = {v.x, v.y, v.z, v.w};
    #pragma unroll
    for (int j = 0; j < 4; ++j) {
        int c = min(max(a[j] - 1, 0), 5);
        atomicAdd(&lh[c], 1);
    }
    __syncthreads();
    if (t < 6) atomicAdd(&counts[t], lh[t]);
}

// ---------------- prep 2: scatter + pack fused ----------------

__global__ __launch_bounds__(256) void k_prepB(const int* __restrict__ command,
                                               const int* __restrict__ counts,
                                               int* __restrict__ cursor2,
                                               int* __restrict__ perm,
                                               const float* __restrict__ sw2,
                                               const float* __restrict__ bw1,
                                               const float* __restrict__ bw2,
                                               const float* __restrict__ ow1,
                                               const float* __restrict__ ow2,
                                               __bf16* __restrict__ PK) {
    int t = threadIdx.x;
    if (blockIdx.x < 256) {
        // ---- scatter ----
        __shared__ int lh[6], lbase[6];
        if (t < 6) lh[t] = 0;
        __syncthreads();
        int i = blockIdx.x * 256 + t;
        int c = command[i] - 1; c = min(max(c, 0), 5);
        int rank = atomicAdd(&lh[c], 1);
        __syncthreads();
        if (t < 6) {
            int base = 0;
            #pragma unroll
            for (int k = 0; k < 6; ++k) base += (k < t) ? counts[k] : 0;
            lbase[t] = base + atomicAdd(&cursor2[t], lh[t]);
        }
        __syncthreads();
        perm[lbase[c] + rank] = i;
        return;
    }
    // ---- pack: W [C][K][N] fp32 -> PK bf16 [kc][n][32k] ----
    int b = blockIdx.x - 256;
    const float* src; int srcN, colOff; unsigned dstOff; int tt;
    if (b < 64)       { int s = b >> 5;        tt = b & 31;  src = sw2;                          srcN = 512; colOff = s * 256; dstOff = PKO_SW2 + s * 65536u; }
    else if (b < 448) { int i = b - 64;  int c = i >> 6; tt = i & 63; src = bw1 + (size_t)c * 512 * 256; srcN = 256; colOff = 0; dstOff = PKO_BW1 + c * 131072u; }
    else if (b < 640) { int i = b - 448; int c = i >> 5; tt = i & 31; src = bw2 + (size_t)c * 256 * 256; srcN = 256; colOff = 0; dstOff = PKO_BW2 + c * 65536u; }
    else if (b < 704) { tt = b - 640; src = ow1; srcN = 256; colOff = 0; dstOff = PKO_OW1; }
    else              { tt = b - 704; src = ow2; srcN = 256; colOff = 0; dstOff = PKO_OW2; }
    int kc = tt >> 2, nt = tt & 3;
    int k0 = kc * 32, n0 = nt * 64;

    __shared__ __bf16 T[64][34];
    #pragma unroll
    for (int p = 0; p < 2; ++p) {
        int idx = p * 256 + t;            // 512 chunks: 32 k x 16 n4
        int k = idx >> 4, n4 = idx & 15;
        float4v v = *(const float4v*)(src + (size_t)(k0 + k) * srcN + colOff + n0 + n4 * 4);
        T[n4 * 4 + 0][k] = (__bf16)v[0];
        T[n4 * 4 + 1][k] = (__bf16)v[1];
        T[n4 * 4 + 2][k] = (__bf16)v[2];
        T[n4 * 4 + 3][k] = (__bf16)v[3];
    }
    __syncthreads();
    int n = t >> 2, seg = t & 3;
    bf16x8 v;
    #pragma unroll
    for (int j = 0; j < 8; ++j) v[j] = T[n][seg * 8 + j];
    *(bf16x8*)(PK + dstOff + ((unsigned)(kc * 256 + n0 + n) * 32u + seg * 8u)) = v;
}

// ---------------- fused main: 64 rows/block, 8 waves, single 64x512 LDS buffer ----------------

__global__ __launch_bounds__(512, 4) void k_fused(
    const float* __restrict__ embedding, const float* __restrict__ speed,
    const int*   __restrict__ command,
    const float* __restrict__ sw1, const float* __restrict__ sb1,
    const float* __restrict__ sb2,
    const float* __restrict__ bb1, const float* __restrict__ bb2,
    const float* __restrict__ bw3, const float* __restrict__ bb3,
    const float* __restrict__ ob1, const float* __restrict__ ob2,
    const float* __restrict__ ow3, const float* __restrict__ ob3,
    const int* __restrict__ perm, const __bf16* __restrict__ PK,
    float* __restrict__ out)
{
    __shared__ __bf16 s_x[64 * PITCH_E];     // 66.6 KB: emb, then [h1|t1]
    __shared__ float  s_head[64][4];
    __shared__ int    s_row[64];
    __shared__ int    s_cmd[64];
    __shared__ float  s_spd[64];

    const int tid = threadIdx.x;
    const int w = tid >> 6, lane = tid & 63;
    const int lm = lane & 15, kg = lane >> 4;
    // XCD-aware swizzle (grid=1024, 8 XCDs, bijective): XCD x gets orig blocks
    // [x*128, (x+1)*128) — contiguous in command-sorted perm -> small L2 set.
    const int obid = ((int)blockIdx.x & 7) * 128 + ((int)blockIdx.x >> 3);
    const int R0 = obid * 64;

    if (tid < 64) {
        int r = perm[R0 + tid];
        s_row[tid] = r;
        int c = command[r] - 1; c = min(max(c, 0), 5);
        s_cmd[tid] = c;
        s_spd[tid] = speed[r];
        s_head[tid][0] = 0.f; s_head[tid][1] = 0.f; s_head[tid][2] = 0.f; s_head[tid][3] = 0.f;
    }
    __syncthreads();

    // ---- stage embedding -> LDS bf16 (NT: evict-first, protect PK in L2) ----
    #pragma unroll
    for (int it = 0; it < 16; ++it) {
        int idx = it * 512 + tid;          // 8192 chunks: 64 rows x 128
        int row = idx >> 7, c4 = idx & 127;
        float4v v = __builtin_nontemporal_load(
            (const float4v*)(embedding + (size_t)s_row[row] * D_ + c4 * 4));
        bf16x4 pv;
        pv[0] = (__bf16)v[0]; pv[1] = (__bf16)v[1];
        pv[2] = (__bf16)v[2]; pv[3] = (__bf16)v[3];
        *(bf16x4*)(s_x + row * PITCH_E + c4 * 4) = pv;
    }
    __syncthreads();

    const int cmin = s_cmd[0], cmax = s_cmd[63];   // perm is bucket-sorted

    // ---- transposed speedMLP: deltaT = sw2T @ shT; vectorized LDS RMW ----
    // wave w owns emb cols w*64..+64 (4 M-tiles); N = 64 rows (4 N-tiles)
    {
        float spd[4];
        #pragma unroll
        for (int nt = 0; nt < 4; ++nt) spd[nt] = s_spd[nt * 16 + lm];
        const unsigned slice = (unsigned)(w >> 2) * 65536u;
        const int mbase = (w & 3) * 64;
        f32x4 dacc[4][4];
        #pragma unroll
        for (int mt = 0; mt < 4; ++mt)
            #pragma unroll
            for (int nt = 0; nt < 4; ++nt) dacc[mt][nt] = f32x4{0.f, 0.f, 0.f, 0.f};
        #pragma unroll 4
        for (int ks = 0; ks < 8; ++ks) {
            const int k0 = ks * 32 + kg * 8;
            float4v w0 = *(const float4v*)(sw1 + k0);
            float4v w1 = *(const float4v*)(sw1 + k0 + 4);
            float4v c0 = *(const float4v*)(sb1 + k0);
            float4v c1 = *(const float4v*)(sb1 + k0 + 4);
            bf16x8 bns[4];
            #pragma unroll
            for (int nt = 0; nt < 4; ++nt)
                #pragma unroll
                for (int j = 0; j < 4; ++j) {
                    bns[nt][j]     = (__bf16)fmaxf(spd[nt] * w0[j] + c0[j], 0.f);
                    bns[nt][j + 4] = (__bf16)fmaxf(spd[nt] * w1[j] + c1[j], 0.f);
                }
            const __bf16* ap = PK + PKO_SW2 + slice + (size_t)ks * 8192
                             + (size_t)(mbase + lm) * 32 + kg * 8;
            __builtin_amdgcn_s_setprio(1);
            #pragma unroll
            for (int mt = 0; mt < 4; ++mt) {
                bf16x8 av = *(const bf16x8*)(ap + mt * 512);
                #pragma unroll
                for (int nt = 0; nt < 4; ++nt)
                    dacc[mt][nt] = __builtin_amdgcn_mfma_f32_16x16x32_bf16(av, bns[nt], dacc[mt][nt], 0, 0, 0);
            }
            __builtin_amdgcn_s_setprio(0);
        }
        // epilogue: lane holds 4 consecutive emb-cols for rows nt*16+lm
        #pragma unroll
        for (int mt = 0; mt < 4; ++mt) {
            int colb = w * 64 + mt * 16 + kg * 4;
            float4v sbv = *(const float4v*)(sb2 + colb);
            #pragma unroll
            for (int nt = 0; nt < 4; ++nt) {
                int row = nt * 16 + lm;
                bf16x4* p = (bf16x4*)(s_x + row * PITCH_E + colb);
                bf16x4 old = *p;
                bf16x4 nv;
                #pragma unroll
                for (int g = 0; g < 4; ++g)
                    nv[g] = (__bf16)(dacc[mt][nt][g] + sbv[g] + (float)old[g]);
                *p = nv;
            }
        }
    }
    __syncthreads();

    const bool roleB = (w < 4);
    const int colbase = (w & 3) * 64;
    const unsigned laneoffB = (unsigned)(colbase + lm) * 32u + kg * 8u;
    const __bf16* aXbase = s_x + lm * PITCH_E + kg * 8;   // + mt*16*PITCH_E

    // ---- phase 3: h1 (waves 0-3, c-loop) | t1 (waves 4-7); results in regs ----
    bf16x4 res[4][4];   // [mt][ct]
    if (roleB) {
        for (int c = cmin; c <= cmax; ++c) {
            const __bf16* bb = PK + PKO_BW1 + (unsigned)c * 131072u + laneoffB;
            f32x4 ah[4][4];
            #pragma unroll
            for (int mt = 0; mt < 4; ++mt)
                #pragma unroll
                for (int ct = 0; ct < 4; ++ct) ah[mt][ct] = f32x4{0.f, 0.f, 0.f, 0.f};
            #pragma unroll 4
            for (int ks = 0; ks < 16; ++ks) {
                bf16x8 a[4];
                #pragma unroll
                for (int mt = 0; mt < 4; ++mt)
                    a[mt] = *(const bf16x8*)(aXbase + mt * 16 * PITCH_E + ks * 32);
                __builtin_amdgcn_s_setprio(1);
                #pragma unroll
                for (int ct = 0; ct < 4; ++ct) {
                    bf16x8 bv = *(const bf16x8*)(bb + (size_t)ks * 8192 + ct * 512);
                    #pragma unroll
                    for (int mt = 0; mt < 4; ++mt)
                        ah[mt][ct] = __builtin_amdgcn_mfma_f32_16x16x32_bf16(a[mt], bv, ah[mt][ct], 0, 0, 0);
                }
                __builtin_amdgcn_s_setprio(0);
            }
            #pragma unroll
            for (int ct = 0; ct < 4; ++ct) {
                int col = colbase + ct * 16 + lm;
                float b = bb1[c * H_ + col];
                #pragma unroll
                for (int mt = 0; mt < 4; ++mt)
                    #pragma unroll
                    for (int g = 0; g < 4; ++g)
                        if (s_cmd[mt * 16 + kg * 4 + g] == c)
                            res[mt][ct][g] = (__bf16)fmaxf(ah[mt][ct][g] + b, 0.f);
            }
        }
    } else {
        const __bf16* bb = PK + PKO_OW1 + laneoffB;
        f32x4 ta[4][4];
        #pragma unroll
        for (int mt = 0; mt < 4; ++mt)
            #pragma unroll
            for (int ct = 0; ct < 4; ++ct) ta[mt][ct] = f32x4{0.f, 0.f, 0.f, 0.f};
        #pragma unroll 4
        for (int ks = 0; ks < 16; ++ks) {
            bf16x8 a[4];
            #pragma unroll
            for (int mt = 0; mt < 4; ++mt)
                a[mt] = *(const bf16x8*)(aXbase + mt * 16 * PITCH_E + ks * 32);
            __builtin_amdgcn_s_setprio(1);
            #pragma unroll
            for (int ct = 0; ct < 4; ++ct) {
                bf16x8 bv = *(const bf16x8*)(bb + (size_t)ks * 8192 + ct * 512);
                #pragma unroll
                for (int mt = 0; mt < 4; ++mt)
                    ta[mt][ct] = __builtin_amdgcn_mfma_f32_16x16x32_bf16(a[mt], bv, ta[mt][ct], 0, 0, 0);
            }
            __builtin_amdgcn_s_setprio(0);
        }
        #pragma unroll
        for (int ct = 0; ct < 4; ++ct) {
            int col = colbase + ct * 16 + lm;
            float b = ob1[col];
            #pragma unroll
            for (int mt = 0; mt < 4; ++mt)
                #pragma unroll
                for (int g = 0; g < 4; ++g)
                    res[mt][ct][g] = (__bf16)fmaxf(ta[mt][ct][g] + b, 0.f);
        }
    }
    __syncthreads();   // all emb reads complete before overwrite

    // ---- write [h1 | t1] back into s_x ----
    {
        const int colW = (roleB ? 0 : 256) + colbase;
        #pragma unroll
        for (int ct = 0; ct < 4; ++ct) {
            int col = colW + ct * 16 + lm;
            #pragma unroll
            for (int mt = 0; mt < 4; ++mt)
                #pragma unroll
                for (int g = 0; g < 4; ++g)
                    s_x[(mt * 16 + kg * 4 + g) * PITCH_E + col] = res[mt][ct][g];
        }
    }
    __syncthreads();

    // ---- phase 4: h2+control (waves 0-3) | t2+speed (waves 4-7), two row-halves ----
    const __bf16* aHbase = s_x + lm * PITCH_E + (roleB ? 0 : 256) + kg * 8;
    if (roleB) {
        for (int c = cmin; c <= cmax; ++c) {
            const __bf16* bb = PK + PKO_BW2 + (unsigned)c * 65536u + laneoffB;
            #pragma unroll
            for (int rh = 0; rh < 2; ++rh) {
                f32x4 hh[2][4];
                #pragma unroll
                for (int mt = 0; mt < 2; ++mt)
                    #pragma unroll
                    for (int ct = 0; ct < 4; ++ct) hh[mt][ct] = f32x4{0.f, 0.f, 0.f, 0.f};
                #pragma unroll 4
                for (int ks = 0; ks < 8; ++ks) {
                    bf16x8 a0 = *(const bf16x8*)(aHbase + (rh * 2 + 0) * 16 * PITCH_E + ks * 32);
                    bf16x8 a1 = *(const bf16x8*)(aHbase + (rh * 2 + 1) * 16 * PITCH_E + ks * 32);
                    __builtin_amdgcn_s_setprio(1);
                    #pragma unroll
                    for (int ct = 0; ct < 4; ++ct) {
                        bf16x8 bv = *(const bf16x8*)(bb + (size_t)ks * 8192 + ct * 512);
                        hh[0][ct] = __builtin_amdgcn_mfma_f32_16x16x32_bf16(a0, bv, hh[0][ct], 0, 0, 0);
                        hh[1][ct] = __builtin_amdgcn_mfma_f32_16x16x32_bf16(a1, bv, hh[1][ct], 0, 0, 0);
                    }
                    __builtin_amdgcn_s_setprio(0);
                }
                float ph[2][4][3];
                #pragma unroll
                for (int mt = 0; mt < 2; ++mt)
                    #pragma unroll
                    for (int g = 0; g < 4; ++g) { ph[mt][g][0] = 0.f; ph[mt][g][1] = 0.f; ph[mt][g][2] = 0.f; }
                #pragma unroll
                for (int ct = 0; ct < 4; ++ct) {
                    int col = colbase + ct * 16 + lm;
                    float b  = bb2[c * H_ + col];
                    float w0 = bw3[(c * H_ + col) * 3 + 0];
                    float w1 = bw3[(c * H_ + col) * 3 + 1];
                    float w2 = bw3[(c * H_ + col) * 3 + 2];
                    #pragma unroll
                    for (int mt = 0; mt < 2; ++mt)
                        #pragma unroll
                        for (int g = 0; g < 4; ++g) {
                            float h = fmaxf(hh[mt][ct][g] + b, 0.f);
                            ph[mt][g][0] += h * w0; ph[mt][g][1] += h * w1; ph[mt][g][2] += h * w2;
                        }
                }
                #pragma unroll
                for (int mt = 0; mt < 2; ++mt)
                    #pragma unroll
                    for (int g = 0; g < 4; ++g)
                        #pragma unroll
                        for (int o = 0; o < 3; ++o) {
                            float v = ph[mt][g][o];
                            v += __shfl_xor(v, 1); v += __shfl_xor(v, 2);
                            v += __shfl_xor(v, 4); v += __shfl_xor(v, 8);
                            ph[mt][g][o] = v;
                        }
                if (lm == 0) {
                    #pragma unroll
                    for (int mt = 0; mt < 2; ++mt)
                        #pragma unroll
                        for (int g = 0; g < 4; ++g) {
                            int row = (rh * 2 + mt) * 16 + kg * 4 + g;
                            if (s_cmd[row] == c) {
                                atomicAdd(&s_head[row][0], ph[mt][g][0]);
                                atomicAdd(&s_head[row][1], ph[mt][g][1]);
                                atomicAdd(&s_head[row][2], ph[mt][g][2]);
                            }
                        }
                }
            }
        }
    } else {
        float sp[4][4];
        #pragma unroll
        for (int mt = 0; mt < 4; ++mt)
            #pragma unroll
            for (int g = 0; g < 4; ++g) sp[mt][g] = 0.f;
        const __bf16* bb = PK + PKO_OW2 + laneoffB;
        #pragma unroll
        for (int rh = 0; rh < 2; ++rh) {
            f32x4 hh[2][4];
            #pragma unroll
            for (int mt = 0; mt < 2; ++mt)
                #pragma unroll
                for (int ct = 0; ct < 4; ++ct) hh[mt][ct] = f32x4{0.f, 0.f, 0.f, 0.f};
            #pragma unroll 4
            for (int ks = 0; ks < 8; ++ks) {
                bf16x8 a0 = *(const bf16x8*)(aHbase + (rh * 2 + 0) * 16 * PITCH_E + ks * 32);
                bf16x8 a1 = *(const bf16x8*)(aHbase + (rh * 2 + 1) * 16 * PITCH_E + ks * 32);
                __builtin_amdgcn_s_setprio(1);
                #pragma unroll
                for (int ct = 0; ct < 4; ++ct) {
                    bf16x8 bv = *(const bf16x8*)(bb + (size_t)ks * 8192 + ct * 512);
                    hh[0][ct] = __builtin_amdgcn_mfma_f32_16x16x32_bf16(a0, bv, hh[0][ct], 0, 0, 0);
                    hh[1][ct] = __builtin_amdgcn_mfma_f32_16x16x32_bf16(a1, bv, hh[1][ct], 0, 0, 0);
                }
                __builtin_amdgcn_s_setprio(0);
            }
            #pragma unroll
            for (int ct = 0; ct < 4; ++ct) {
                int col = colbase + ct * 16 + lm;
                float b = ob2[col], wv = ow3[col];
                #pragma unroll
                for (int mt = 0; mt < 2; ++mt)
                    #pragma unroll
                    for (int g = 0; g < 4; ++g)
                        sp[rh * 2 + mt][g] += fmaxf(hh[mt][ct][g] + b, 0.f) * wv;
            }
        }
        #pragma unroll
        for (int mt = 0; mt < 4; ++mt)
            #pragma unroll
            for (int g = 0; g < 4; ++g) {
                float v = sp[mt][g];
                v += __shfl_xor(v, 1); v += __shfl_xor(v, 2);
                v += __shfl_xor(v, 4); v += __shfl_xor(v, 8);
                if (lm == 0) atomicAdd(&s_head[mt * 16 + kg * 4 + g][3], v);
            }
    }
    __syncthreads();

    if (tid < 64) {
        int r = s_row[tid], c = s_cmd[tid];
        #pragma unroll
        for (int o = 0; o < 3; ++o) {
            float x = s_head[tid][o] + bb3[c * 3 + o];
            __builtin_nontemporal_store(1.f / (1.f + __expf(-x)), &out[(size_t)r * 3 + o]);
        }
        __builtin_nontemporal_store(s_head[tid][3] + ob3[0], &out[(size_t)3 * B_ + r]);
    }
}

// ---------------- fallback (fp32, no ws) ----------------

__global__ __launch_bounds__(256) void cilrs_slow(
    const float* __restrict__ embedding, const float* __restrict__ speed,
    const int* __restrict__ command,
    const float* __restrict__ sw1, const float* __restrict__ sb1,
    const float* __restrict__ sw2, const float* __restrict__ sb2,
    const float* __restrict__ bw1, const float* __restrict__ bb1,
    const float* __restrict__ bw2, const float* __restrict__ bb2,
    const float* __restrict__ bw3, const float* __restrict__ bb3,
    const float* __restrict__ ow1, const float* __restrict__ ob1,
    const float* __restrict__ ow2, const float* __restrict__ ob2,
    const float* __restrict__ ow3, const float* __restrict__ ob3,
    float* __restrict__ out)
{
    const int row = blockIdx.x;
    const int j   = threadIdx.x;
    __shared__ float sh[H_];
    __shared__ float emb[D_];
    __shared__ float h1[H_];
    __shared__ float h2[H_];
    const float spd = speed[row];
    { float v = spd * sw1[j] + sb1[j]; sh[j] = v > 0.f ? v : 0.f; }
    __syncthreads();
    {
        float a0 = 0.f, a1 = 0.f;
        for (int h = 0; h < H_; ++h) {
            const float s = sh[h];
            a0 += s * sw2[h * D_ + j];
            a1 += s * sw2[h * D_ + j + 256];
        }
        emb[j]       = embedding[(size_t)row * D_ + j]       + a0 + sb2[j];
        emb[j + 256] = embedding[(size_t)row * D_ + j + 256] + a1 + sb2[j + 256];
    }
    __syncthreads();
    const int n = command[row] - 1;
    {
        const float* wp = bw1 + (size_t)n * D_ * H_;
        float a = 0.f;
        for (int d = 0; d < D_; ++d) a += emb[d] * wp[d * H_ + j];
        a += bb1[n * H_ + j];
        h1[j] = a > 0.f ? a : 0.f;
    }
    __syncthreads();
    {
        const float* wp = bw2 + (size_t)n * H_ * H_;
        float a = 0.f;
        for (int h = 0; h < H_; ++h) a += h1[h] * wp[h * H_ + j];
        a += bb2[n * H_ + j];
        h2[j] = a > 0.f ? a : 0.f;
    }
    __syncthreads();
    {
        float a = 0.f;
        for (int d = 0; d < D_; ++d) a += emb[d] * ow1[d * H_ + j];
        a += ob1[j];
        sh[j] = a > 0.f ? a : 0.f;
    }
    __syncthreads();
    {
        float a = 0.f;
        for (int h = 0; h < H_; ++h) a += sh[h] * ow2[h * H_ + j];
        a += ob2[j];
        h1[j] = a > 0.f ? a : 0.f;
    }
    __syncthreads();
    if (j < 3) {
        const float* wp = bw3 + (size_t)n * H_ * 3;
        float a = 0.f;
        for (int h = 0; h < H_; ++h) a += h2[h] * wp[h * 3 + j];
        a += bb3[n * 3 + j];
        out[(size_t)row * 3 + j] = 1.f / (1.f + expf(-a));
    } else if (j == 3) {
        float a = 0.f;
        for (int h = 0; h < H_; ++h) a += h1[h] * ow3[h];
        a += ob3[0];
        out[(size_t)B_ * 3 + row] = a;
    }
}

// ---------------- launch ----------------

extern "C" void kernel_launch(void* const* d_in, const int* in_sizes, int n_in,
                              void* d_out, int out_size, void* d_ws, size_t ws_size,
                              hipStream_t stream) {
    const float* embedding = (const float*)d_in[0];
    const float* speed     = (const float*)d_in[1];
    const int*   command   = (const int*)  d_in[2];
    const float* sw1 = (const float*)d_in[3];
    const float* sb1 = (const float*)d_in[4];
    const float* sw2 = (const float*)d_in[5];
    const float* sb2 = (const float*)d_in[6];
    const float* bw1 = (const float*)d_in[7];
    const float* bb1 = (const float*)d_in[8];
    const float* bw2 = (const float*)d_in[9];
    const float* bb2 = (const float*)d_in[10];
    const float* bw3 = (const float*)d_in[11];
    const float* bb3 = (const float*)d_in[12];
    const float* ow1 = (const float*)d_in[13];
    const float* ob1 = (const float*)d_in[14];
    const float* ow2 = (const float*)d_in[15];
    const float* ob2 = (const float*)d_in[16];
    const float* ow3 = (const float*)d_in[17];
    const float* ob3 = (const float*)d_in[18];
    float* out = (float*)d_out;

    if (ws_size < (size_t)WS_NEEDED) {
        cilrs_slow<<<B_, 256, 0, stream>>>(embedding, speed, command,
                                           sw1, sb1, sw2, sb2,
                                           bw1, bb1, bw2, bb2, bw3, bb3,
                                           ow1, ob1, ow2, ob2, ow3, ob3, out);
        return;
    }

    char* ws = (char*)d_ws;
    int*    counts  = (int*)    ws;          // [0..23]
    int*    cursor2 = (int*)   (ws + 24);    // [24..47]
    int*    perm    = (int*)   (ws + OFF_PERM);
    __bf16* PK      = (__bf16*)(ws + OFF_PACK);

    hipMemsetAsync(ws, 0, 64, stream);
    k_count<<<64, 256, 0, stream>>>(command, counts);
    k_prepB<<<992, 256, 0, stream>>>(command, counts, cursor2, perm,
                                     sw2, bw1, bw2, ow1, ow2, PK);
    k_fused<<<B_ / 64, 512, 0, stream>>>(embedding, speed, command,
                                         sw1, sb1, sb2,
                                         bb1, bb2, bw3, bb3,
                                         ob1, ob2, ow3, ob3,
                                         perm, PK, out);
}

// Round 9
// 332.981 us; speedup vs baseline: 1.1239x; 1.0566x over previous
//
#include <hip/hip_runtime.h>
#include <math.h>

// CILRS fused head — round 16.
//  Base = round 15 (159 µs k_fused; XCD swizzle kept). New lever: free the
//  register wall. AGPR accumulators (64) + VGPR (64) were pinned at the 128
//  unified cap -> compiler couldn't pipeline B-loads (VGPR stuck at 64 for 5
//  rounds). Split accumulator loops into two passes:
//   - phase 1: mt-split  -> dacc[2][4] = 32 AGPR (bns recomputed per pass)
//   - phase 3: ct-split  -> ah[4][2]  = 32 AGPR (A re-read from LDS per pass)
//  Freed ~32 regs let unroll-4 hold 2-3x more B-bytes in flight.
//  Keep: 64-row/512-thr/2-blk-CU, XCD swizzle, NT emb loads, setprio, k_count.

#define B_ 65536
#define D_ 512
#define H_ 256

typedef float  f32x4   __attribute__((ext_vector_type(4)));
typedef __bf16 bf16x8  __attribute__((ext_vector_type(8)));
typedef __bf16 bf16x4  __attribute__((ext_vector_type(4)));
typedef float  float4v __attribute__((ext_vector_type(4)));

// ---- ws layout (bytes) ----
// [0..23]  counts[6]   (zeroed by hipMemsetAsync)
// [24..47] cursor2[6]  (zeroed by hipMemsetAsync)
#define OFF_PERM     256        // 65536 ints
#define OFF_PACK     262400     // packed bf16 weights (3,014,656 B)
#define WS_NEEDED    3277056

// packed element offsets (bf16 elements, relative to PK); layout [kc][n][32k]
#define PKO_SW2   0u
#define PKO_BW1   131072u
#define PKO_BW2   917504u
#define PKO_OW1   1310720u
#define PKO_OW2   1441792u

#define PITCH_E 520   // row pitch (bf16) for the 64x512 tile

// ---------------- prep 1: 64-block histogram ----------------

__global__ __launch_bounds__(256) void k_count(const int* __restrict__ command,
                                               int* __restrict__ counts) {
    __shared__ int lh[6];
    int t = threadIdx.x;
    if (t < 6) lh[t] = 0;
    __syncthreads();
    int i = blockIdx.x * 256 + t;
    int4 v = ((const int4*)command)[i];
    int a[4] = {v.x, v.y, v.z, v.w};
    #pragma unroll
    for (int j = 0; j < 4; ++j) {
        int c = min(max(a[j] - 1, 0), 5);
        atomicAdd(&lh[c], 1);
    }
    __syncthreads();
    if (t < 6) atomicAdd(&counts[t], lh[t]);
}

// ---------------- prep 2: scatter + pack fused ----------------

__global__ __launch_bounds__(256) void k_prepB(const int* __restrict__ command,
                                               const int* __restrict__ counts,
                                               int* __restrict__ cursor2,
                                               int* __restrict__ perm,
                                               const float* __restrict__ sw2,
                                               const float* __restrict__ bw1,
                                               const float* __restrict__ bw2,
                                               const float* __restrict__ ow1,
                                               const float* __restrict__ ow2,
                                               __bf16* __restrict__ PK) {
    int t = threadIdx.x;
    if (blockIdx.x < 256) {
        // ---- scatter ----
        __shared__ int lh[6], lbase[6];
        if (t < 6) lh[t] = 0;
        __syncthreads();
        int i = blockIdx.x * 256 + t;
        int c = command[i] - 1; c = min(max(c, 0), 5);
        int rank = atomicAdd(&lh[c], 1);
        __syncthreads();
        if (t < 6) {
            int base = 0;
            #pragma unroll
            for (int k = 0; k < 6; ++k) base += (k < t) ? counts[k] : 0;
            lbase[t] = base + atomicAdd(&cursor2[t], lh[t]);
        }
        __syncthreads();
        perm[lbase[c] + rank] = i;
        return;
    }
    // ---- pack: W [C][K][N] fp32 -> PK bf16 [kc][n][32k] ----
    int b = blockIdx.x - 256;
    const float* src; int srcN, colOff; unsigned dstOff; int tt;
    if (b < 64)       { int s = b >> 5;        tt = b & 31;  src = sw2;                          srcN = 512; colOff = s * 256; dstOff = PKO_SW2 + s * 65536u; }
    else if (b < 448) { int i = b - 64;  int c = i >> 6; tt = i & 63; src = bw1 + (size_t)c * 512 * 256; srcN = 256; colOff = 0; dstOff = PKO_BW1 + c * 131072u; }
    else if (b < 640) { int i = b - 448; int c = i >> 5; tt = i & 31; src = bw2 + (size_t)c * 256 * 256; srcN = 256; colOff = 0; dstOff = PKO_BW2 + c * 65536u; }
    else if (b < 704) { tt = b - 640; src = ow1; srcN = 256; colOff = 0; dstOff = PKO_OW1; }
    else              { tt = b - 704; src = ow2; srcN = 256; colOff = 0; dstOff = PKO_OW2; }
    int kc = tt >> 2, nt = tt & 3;
    int k0 = kc * 32, n0 = nt * 64;

    __shared__ __bf16 T[64][34];
    #pragma unroll
    for (int p = 0; p < 2; ++p) {
        int idx = p * 256 + t;            // 512 chunks: 32 k x 16 n4
        int k = idx >> 4, n4 = idx & 15;
        float4v v = *(const float4v*)(src + (size_t)(k0 + k) * srcN + colOff + n0 + n4 * 4);
        T[n4 * 4 + 0][k] = (__bf16)v[0];
        T[n4 * 4 + 1][k] = (__bf16)v[1];
        T[n4 * 4 + 2][k] = (__bf16)v[2];
        T[n4 * 4 + 3][k] = (__bf16)v[3];
    }
    __syncthreads();
    int n = t >> 2, seg = t & 3;
    bf16x8 v;
    #pragma unroll
    for (int j = 0; j < 8; ++j) v[j] = T[n][seg * 8 + j];
    *(bf16x8*)(PK + dstOff + ((unsigned)(kc * 256 + n0 + n) * 32u + seg * 8u)) = v;
}

// ---------------- fused main: 64 rows/block, 8 waves, single 64x512 LDS buffer ----------------

__global__ __launch_bounds__(512, 4) void k_fused(
    const float* __restrict__ embedding, const float* __restrict__ speed,
    const int*   __restrict__ command,
    const float* __restrict__ sw1, const float* __restrict__ sb1,
    const float* __restrict__ sb2,
    const float* __restrict__ bb1, const float* __restrict__ bb2,
    const float* __restrict__ bw3, const float* __restrict__ bb3,
    const float* __restrict__ ob1, const float* __restrict__ ob2,
    const float* __restrict__ ow3, const float* __restrict__ ob3,
    const int* __restrict__ perm, const __bf16* __restrict__ PK,
    float* __restrict__ out)
{
    __shared__ __bf16 s_x[64 * PITCH_E];     // 66.6 KB: emb, then [h1|t1]
    __shared__ float  s_head[64][4];
    __shared__ int    s_row[64];
    __shared__ int    s_cmd[64];
    __shared__ float  s_spd[64];

    const int tid = threadIdx.x;
    const int w = tid >> 6, lane = tid & 63;
    const int lm = lane & 15, kg = lane >> 4;
    // XCD-aware swizzle (grid=1024, 8 XCDs, bijective): XCD x gets orig blocks
    // [x*128, (x+1)*128) — contiguous in command-sorted perm -> small L2 set.
    const int obid = ((int)blockIdx.x & 7) * 128 + ((int)blockIdx.x >> 3);
    const int R0 = obid * 64;

    if (tid < 64) {
        int r = perm[R0 + tid];
        s_row[tid] = r;
        int c = command[r] - 1; c = min(max(c, 0), 5);
        s_cmd[tid] = c;
        s_spd[tid] = speed[r];
        s_head[tid][0] = 0.f; s_head[tid][1] = 0.f; s_head[tid][2] = 0.f; s_head[tid][3] = 0.f;
    }
    __syncthreads();

    // ---- stage embedding -> LDS bf16 (NT: evict-first, protect PK in L2) ----
    #pragma unroll
    for (int it = 0; it < 16; ++it) {
        int idx = it * 512 + tid;          // 8192 chunks: 64 rows x 128
        int row = idx >> 7, c4 = idx & 127;
        float4v v = __builtin_nontemporal_load(
            (const float4v*)(embedding + (size_t)s_row[row] * D_ + c4 * 4));
        bf16x4 pv;
        pv[0] = (__bf16)v[0]; pv[1] = (__bf16)v[1];
        pv[2] = (__bf16)v[2]; pv[3] = (__bf16)v[3];
        *(bf16x4*)(s_x + row * PITCH_E + c4 * 4) = pv;
    }
    __syncthreads();

    const int cmin = s_cmd[0], cmax = s_cmd[63];   // perm is bucket-sorted

    // ---- transposed speedMLP: deltaT = sw2T @ shT; mt-split (32 AGPR) ----
    // wave w owns emb cols w*64..+64 (4 M-tiles, 2 per pass); N = 64 rows
    {
        float spd[4];
        #pragma unroll
        for (int nt = 0; nt < 4; ++nt) spd[nt] = s_spd[nt * 16 + lm];
        const unsigned slice = (unsigned)(w >> 2) * 65536u;
        const int mbase = (w & 3) * 64;
        #pragma unroll
        for (int mh = 0; mh < 2; ++mh) {
            f32x4 dacc[2][4];
            #pragma unroll
            for (int mt = 0; mt < 2; ++mt)
                #pragma unroll
                for (int nt = 0; nt < 4; ++nt) dacc[mt][nt] = f32x4{0.f, 0.f, 0.f, 0.f};
            #pragma unroll 4
            for (int ks = 0; ks < 8; ++ks) {
                const int k0 = ks * 32 + kg * 8;
                float4v w0 = *(const float4v*)(sw1 + k0);
                float4v w1 = *(const float4v*)(sw1 + k0 + 4);
                float4v c0 = *(const float4v*)(sb1 + k0);
                float4v c1 = *(const float4v*)(sb1 + k0 + 4);
                bf16x8 bns[4];
                #pragma unroll
                for (int nt = 0; nt < 4; ++nt)
                    #pragma unroll
                    for (int j = 0; j < 4; ++j) {
                        bns[nt][j]     = (__bf16)fmaxf(spd[nt] * w0[j] + c0[j], 0.f);
                        bns[nt][j + 4] = (__bf16)fmaxf(spd[nt] * w1[j] + c1[j], 0.f);
                    }
                const __bf16* ap = PK + PKO_SW2 + slice + (size_t)ks * 8192
                                 + (size_t)(mbase + lm) * 32 + kg * 8;
                __builtin_amdgcn_s_setprio(1);
                #pragma unroll
                for (int mt2 = 0; mt2 < 2; ++mt2) {
                    bf16x8 av = *(const bf16x8*)(ap + (mh * 2 + mt2) * 512);
                    #pragma unroll
                    for (int nt = 0; nt < 4; ++nt)
                        dacc[mt2][nt] = __builtin_amdgcn_mfma_f32_16x16x32_bf16(av, bns[nt], dacc[mt2][nt], 0, 0, 0);
                }
                __builtin_amdgcn_s_setprio(0);
            }
            // epilogue: lane holds 4 consecutive emb-cols for rows nt*16+lm
            #pragma unroll
            for (int mt2 = 0; mt2 < 2; ++mt2) {
                int colb = w * 64 + (mh * 2 + mt2) * 16 + kg * 4;
                float4v sbv = *(const float4v*)(sb2 + colb);
                #pragma unroll
                for (int nt = 0; nt < 4; ++nt) {
                    int row = nt * 16 + lm;
                    bf16x4* p = (bf16x4*)(s_x + row * PITCH_E + colb);
                    bf16x4 old = *p;
                    bf16x4 nv;
                    #pragma unroll
                    for (int g = 0; g < 4; ++g)
                        nv[g] = (__bf16)(dacc[mt2][nt][g] + sbv[g] + (float)old[g]);
                    *p = nv;
                }
            }
        }
    }
    __syncthreads();

    const bool roleB = (w < 4);
    const int colbase = (w & 3) * 64;
    const unsigned laneoffB = (unsigned)(colbase + lm) * 32u + kg * 8u;
    const __bf16* aXbase = s_x + lm * PITCH_E + kg * 8;   // + mt*16*PITCH_E

    // ---- phase 3: h1 (waves 0-3, c-loop) | t1 (waves 4-7); ct-split (32 AGPR) ----
    bf16x4 res[4][4];   // [mt][ct]
    if (roleB) {
        for (int c = cmin; c <= cmax; ++c) {
            const __bf16* bb = PK + PKO_BW1 + (unsigned)c * 131072u + laneoffB;
            #pragma unroll
            for (int ch = 0; ch < 2; ++ch) {
                f32x4 ah[4][2];
                #pragma unroll
                for (int mt = 0; mt < 4; ++mt) {
                    ah[mt][0] = f32x4{0.f, 0.f, 0.f, 0.f};
                    ah[mt][1] = f32x4{0.f, 0.f, 0.f, 0.f};
                }
                #pragma unroll 4
                for (int ks = 0; ks < 16; ++ks) {
                    bf16x8 a[4];
                    #pragma unroll
                    for (int mt = 0; mt < 4; ++mt)
                        a[mt] = *(const bf16x8*)(aXbase + mt * 16 * PITCH_E + ks * 32);
                    __builtin_amdgcn_s_setprio(1);
                    #pragma unroll
                    for (int ct2 = 0; ct2 < 2; ++ct2) {
                        bf16x8 bv = *(const bf16x8*)(bb + (size_t)ks * 8192 + (ch * 2 + ct2) * 512);
                        #pragma unroll
                        for (int mt = 0; mt < 4; ++mt)
                            ah[mt][ct2] = __builtin_amdgcn_mfma_f32_16x16x32_bf16(a[mt], bv, ah[mt][ct2], 0, 0, 0);
                    }
                    __builtin_amdgcn_s_setprio(0);
                }
                #pragma unroll
                for (int ct2 = 0; ct2 < 2; ++ct2) {
                    int ct = ch * 2 + ct2;
                    int col = colbase + ct * 16 + lm;
                    float b = bb1[c * H_ + col];
                    #pragma unroll
                    for (int mt = 0; mt < 4; ++mt)
                        #pragma unroll
                        for (int g = 0; g < 4; ++g)
                            if (s_cmd[mt * 16 + kg * 4 + g] == c)
                                res[mt][ct][g] = (__bf16)fmaxf(ah[mt][ct2][g] + b, 0.f);
                }
            }
        }
    } else {
        const __bf16* bb = PK + PKO_OW1 + laneoffB;
        #pragma unroll
        for (int ch = 0; ch < 2; ++ch) {
            f32x4 ta[4][2];
            #pragma unroll
            for (int mt = 0; mt < 4; ++mt) {
                ta[mt][0] = f32x4{0.f, 0.f, 0.f, 0.f};
                ta[mt][1] = f32x4{0.f, 0.f, 0.f, 0.f};
            }
            #pragma unroll 4
            for (int ks = 0; ks < 16; ++ks) {
                bf16x8 a[4];
                #pragma unroll
                for (int mt = 0; mt < 4; ++mt)
                    a[mt] = *(const bf16x8*)(aXbase + mt * 16 * PITCH_E + ks * 32);
                __builtin_amdgcn_s_setprio(1);
                #pragma unroll
                for (int ct2 = 0; ct2 < 2; ++ct2) {
                    bf16x8 bv = *(const bf16x8*)(bb + (size_t)ks * 8192 + (ch * 2 + ct2) * 512);
                    #pragma unroll
                    for (int mt = 0; mt < 4; ++mt)
                        ta[mt][ct2] = __builtin_amdgcn_mfma_f32_16x16x32_bf16(a[mt], bv, ta[mt][ct2], 0, 0, 0);
                }
                __builtin_amdgcn_s_setprio(0);
            }
            #pragma unroll
            for (int ct2 = 0; ct2 < 2; ++ct2) {
                int ct = ch * 2 + ct2;
                int col = colbase + ct * 16 + lm;
                float b = ob1[col];
                #pragma unroll
                for (int mt = 0; mt < 4; ++mt)
                    #pragma unroll
                    for (int g = 0; g < 4; ++g)
                        res[mt][ct][g] = (__bf16)fmaxf(ta[mt][ct2][g] + b, 0.f);
            }
        }
    }
    __syncthreads();   // all emb reads complete before overwrite

    // ---- write [h1 | t1] back into s_x ----
    {
        const int colW = (roleB ? 0 : 256) + colbase;
        #pragma unroll
        for (int ct = 0; ct < 4; ++ct) {
            int col = colW + ct * 16 + lm;
            #pragma unroll
            for (int mt = 0; mt < 4; ++mt)
                #pragma unroll
                for (int g = 0; g < 4; ++g)
                    s_x[(mt * 16 + kg * 4 + g) * PITCH_E + col] = res[mt][ct][g];
        }
    }
    __syncthreads();

    // ---- phase 4: h2+control (waves 0-3) | t2+speed (waves 4-7), two row-halves ----
    const __bf16* aHbase = s_x + lm * PITCH_E + (roleB ? 0 : 256) + kg * 8;
    if (roleB) {
        for (int c = cmin; c <= cmax; ++c) {
            const __bf16* bb = PK + PKO_BW2 + (unsigned)c * 65536u + laneoffB;
            #pragma unroll
            for (int rh = 0; rh < 2; ++rh) {
                f32x4 hh[2][4];
                #pragma unroll
                for (int mt = 0; mt < 2; ++mt)
                    #pragma unroll
                    for (int ct = 0; ct < 4; ++ct) hh[mt][ct] = f32x4{0.f, 0.f, 0.f, 0.f};
                #pragma unroll 4
                for (int ks = 0; ks < 8; ++ks) {
                    bf16x8 a0 = *(const bf16x8*)(aHbase + (rh * 2 + 0) * 16 * PITCH_E + ks * 32);
                    bf16x8 a1 = *(const bf16x8*)(aHbase + (rh * 2 + 1) * 16 * PITCH_E + ks * 32);
                    __builtin_amdgcn_s_setprio(1);
                    #pragma unroll
                    for (int ct = 0; ct < 4; ++ct) {
                        bf16x8 bv = *(const bf16x8*)(bb + (size_t)ks * 8192 + ct * 512);
                        hh[0][ct] = __builtin_amdgcn_mfma_f32_16x16x32_bf16(a0, bv, hh[0][ct], 0, 0, 0);
                        hh[1][ct] = __builtin_amdgcn_mfma_f32_16x16x32_bf16(a1, bv, hh[1][ct], 0, 0, 0);
                    }
                    __builtin_amdgcn_s_setprio(0);
                }
                float ph[2][4][3];
                #pragma unroll
                for (int mt = 0; mt < 2; ++mt)
                    #pragma unroll
                    for (int g = 0; g < 4; ++g) { ph[mt][g][0] = 0.f; ph[mt][g][1] = 0.f; ph[mt][g][2] = 0.f; }
                #pragma unroll
                for (int ct = 0; ct < 4; ++ct) {
                    int col = colbase + ct * 16 + lm;
                    float b  = bb2[c * H_ + col];
                    float w0 = bw3[(c * H_ + col) * 3 + 0];
                    float w1 = bw3[(c * H_ + col) * 3 + 1];
                    float w2 = bw3[(c * H_ + col) * 3 + 2];
                    #pragma unroll
                    for (int mt = 0; mt < 2; ++mt)
                        #pragma unroll
                        for (int g = 0; g < 4; ++g) {
                            float h = fmaxf(hh[mt][ct][g] + b, 0.f);
                            ph[mt][g][0] += h * w0; ph[mt][g][1] += h * w1; ph[mt][g][2] += h * w2;
                        }
                }
                #pragma unroll
                for (int mt = 0; mt < 2; ++mt)
                    #pragma unroll
                    for (int g = 0; g < 4; ++g)
                        #pragma unroll
                        for (int o = 0; o < 3; ++o) {
                            float v = ph[mt][g][o];
                            v += __shfl_xor(v, 1); v += __shfl_xor(v, 2);
                            v += __shfl_xor(v, 4); v += __shfl_xor(v, 8);
                            ph[mt][g][o] = v;
                        }
                if (lm == 0) {
                    #pragma unroll
                    for (int mt = 0; mt < 2; ++mt)
                        #pragma unroll
                        for (int g = 0; g < 4; ++g) {
                            int row = (rh * 2 + mt) * 16 + kg * 4 + g;
                            if (s_cmd[row] == c) {
                                atomicAdd(&s_head[row][0], ph[mt][g][0]);
                                atomicAdd(&s_head[row][1], ph[mt][g][1]);
                                atomicAdd(&s_head[row][2], ph[mt][g][2]);
                            }
                        }
                }
            }
        }
    } else {
        float sp[4][4];
        #pragma unroll
        for (int mt = 0; mt < 4; ++mt)
            #pragma unroll
            for (int g = 0; g < 4; ++g) sp[mt][g] = 0.f;
        const __bf16* bb = PK + PKO_OW2 + laneoffB;
        #pragma unroll
        for (int rh = 0; rh < 2; ++rh) {
            f32x4 hh[2][4];
            #pragma unroll
            for (int mt = 0; mt < 2; ++mt)
                #pragma unroll
                for (int ct = 0; ct < 4; ++ct) hh[mt][ct] = f32x4{0.f, 0.f, 0.f, 0.f};
            #pragma unroll 4
            for (int ks = 0; ks < 8; ++ks) {
                bf16x8 a0 = *(const bf16x8*)(aHbase + (rh * 2 + 0) * 16 * PITCH_E + ks * 32);
                bf16x8 a1 = *(const bf16x8*)(aHbase + (rh * 2 + 1) * 16 * PITCH_E + ks * 32);
                __builtin_amdgcn_s_setprio(1);
                #pragma unroll
                for (int ct = 0; ct < 4; ++ct) {
                    bf16x8 bv = *(const bf16x8*)(bb + (size_t)ks * 8192 + ct * 512);
                    hh[0][ct] = __builtin_amdgcn_mfma_f32_16x16x32_bf16(a0, bv, hh[0][ct], 0, 0, 0);
                    hh[1][ct] = __builtin_amdgcn_mfma_f32_16x16x32_bf16(a1, bv, hh[1][ct], 0, 0, 0);
                }
                __builtin_amdgcn_s_setprio(0);
            }
            #pragma unroll
            for (int ct = 0; ct < 4; ++ct) {
                int col = colbase + ct * 16 + lm;
                float b = ob2[col], wv = ow3[col];
                #pragma unroll
                for (int mt = 0; mt < 2; ++mt)
                    #pragma unroll
                    for (int g = 0; g < 4; ++g)
                        sp[rh * 2 + mt][g] += fmaxf(hh[mt][ct][g] + b, 0.f) * wv;
            }
        }
        #pragma unroll
        for (int mt = 0; mt < 4; ++mt)
            #pragma unroll
            for (int g = 0; g < 4; ++g) {
                float v = sp[mt][g];
                v += __shfl_xor(v, 1); v += __shfl_xor(v, 2);
                v += __shfl_xor(v, 4); v += __shfl_xor(v, 8);
                if (lm == 0) atomicAdd(&s_head[mt * 16 + kg * 4 + g][3], v);
            }
    }
    __syncthreads();

    if (tid < 64) {
        int r = s_row[tid], c = s_cmd[tid];
        #pragma unroll
        for (int o = 0; o < 3; ++o) {
            float x = s_head[tid][o] + bb3[c * 3 + o];
            __builtin_nontemporal_store(1.f / (1.f + __expf(-x)), &out[(size_t)r * 3 + o]);
        }
        __builtin_nontemporal_store(s_head[tid][3] + ob3[0], &out[(size_t)3 * B_ + r]);
    }
}

// ---------------- fallback (fp32, no ws) ----------------

__global__ __launch_bounds__(256) void cilrs_slow(
    const float* __restrict__ embedding, const float* __restrict__ speed,
    const int* __restrict__ command,
    const float* __restrict__ sw1, const float* __restrict__ sb1,
    const float* __restrict__ sw2, const float* __restrict__ sb2,
    const float* __restrict__ bw1, const float* __restrict__ bb1,
    const float* __restrict__ bw2, const float* __restrict__ bb2,
    const float* __restrict__ bw3, const float* __restrict__ bb3,
    const float* __restrict__ ow1, const float* __restrict__ ob1,
    const float* __restrict__ ow2, const float* __restrict__ ob2,
    const float* __restrict__ ow3, const float* __restrict__ ob3,
    float* __restrict__ out)
{
    const int row = blockIdx.x;
    const int j   = threadIdx.x;
    __shared__ float sh[H_];
    __shared__ float emb[D_];
    __shared__ float h1[H_];
    __shared__ float h2[H_];
    const float spd = speed[row];
    { float v = spd * sw1[j] + sb1[j]; sh[j] = v > 0.f ? v : 0.f; }
    __syncthreads();
    {
        float a0 = 0.f, a1 = 0.f;
        for (int h = 0; h < H_; ++h) {
            const float s = sh[h];
            a0 += s * sw2[h * D_ + j];
            a1 += s * sw2[h * D_ + j + 256];
        }
        emb[j]       = embedding[(size_t)row * D_ + j]       + a0 + sb2[j];
        emb[j + 256] = embedding[(size_t)row * D_ + j + 256] + a1 + sb2[j + 256];
    }
    __syncthreads();
    const int n = command[row] - 1;
    {
        const float* wp = bw1 + (size_t)n * D_ * H_;
        float a = 0.f;
        for (int d = 0; d < D_; ++d) a += emb[d] * wp[d * H_ + j];
        a += bb1[n * H_ + j];
        h1[j] = a > 0.f ? a : 0.f;
    }
    __syncthreads();
    {
        const float* wp = bw2 + (size_t)n * H_ * H_;
        float a = 0.f;
        for (int h = 0; h < H_; ++h) a += h1[h] * wp[h * H_ + j];
        a += bb2[n * H_ + j];
        h2[j] = a > 0.f ? a : 0.f;
    }
    __syncthreads();
    {
        float a = 0.f;
        for (int d = 0; d < D_; ++d) a += emb[d] * ow1[d * H_ + j];
        a += ob1[j];
        sh[j] = a > 0.f ? a : 0.f;
    }
    __syncthreads();
    {
        float a = 0.f;
        for (int h = 0; h < H_; ++h) a += sh[h] * ow2[h * H_ + j];
        a += ob2[j];
        h1[j] = a > 0.f ? a : 0.f;
    }
    __syncthreads();
    if (j < 3) {
        const float* wp = bw3 + (size_t)n * H_ * 3;
        float a = 0.f;
        for (int h = 0; h < H_; ++h) a += h2[h] * wp[h * 3 + j];
        a += bb3[n * 3 + j];
        out[(size_t)row * 3 + j] = 1.f / (1.f + expf(-a));
    } else if (j == 3) {
        float a = 0.f;
        for (int h = 0; h < H_; ++h) a += h1[h] * ow3[h];
        a += ob3[0];
        out[(size_t)B_ * 3 + row] = a;
    }
}

// ---------------- launch ----------------

extern "C" void kernel_launch(void* const* d_in, const int* in_sizes, int n_in,
                              void* d_out, int out_size, void* d_ws, size_t ws_size,
                              hipStream_t stream) {
    const float* embedding = (const float*)d_in[0];
    const float* speed     = (const float*)d_in[1];
    const int*   command   = (const int*)  d_in[2];
    const float* sw1 = (const float*)d_in[3];
    const float* sb1 = (const float*)d_in[4];
    const float* sw2 = (const float*)d_in[5];
    const float* sb2 = (const float*)d_in[6];
    const float* bw1 = (const float*)d_in[7];
    const float* bb1 = (const float*)d_in[8];
    const float* bw2 = (const float*)d_in[9];
    const float* bb2 = (const float*)d_in[10];
    const float* bw3 = (const float*)d_in[11];
    const float* bb3 = (const float*)d_in[12];
    const float* ow1 = (const float*)d_in[13];
    const float* ob1 = (const float*)d_in[14];
    const float* ow2 = (const float*)d_in[15];
    const float* ob2 = (const float*)d_in[16];
    const float* ow3 = (const float*)d_in[17];
    const float* ob3 = (const float*)d_in[18];
    float* out = (float*)d_out;

    if (ws_size < (size_t)WS_NEEDED) {
        cilrs_slow<<<B_, 256, 0, stream>>>(embedding, speed, command,
                                           sw1, sb1, sw2, sb2,
                                           bw1, bb1, bw2, bb2, bw3, bb3,
                                           ow1, ob1, ow2, ob2, ow3, ob3, out);
        return;
    }

    char* ws = (char*)d_ws;
    int*    counts  = (int*)    ws;          // [0..23]
    int*    cursor2 = (int*)   (ws + 24);    // [24..47]
    int*    perm    = (int*)   (ws + OFF_PERM);
    __bf16* PK      = (__bf16*)(ws + OFF_PACK);

    hipMemsetAsync(ws, 0, 64, stream);
    k_count<<<64, 256, 0, stream>>>(command, counts);
    k_prepB<<<992, 256, 0, stream>>>(command, counts, cursor2, perm,
                                     sw2, bw1, bw2, ow1, ow2, PK);
    k_fused<<<B_ / 64, 512, 0, stream>>>(embedding, speed, command,
                                         sw1, sb1, sb2,
                                         bb1, bb2, bw3, bb3,
                                         ob1, ob2, ow3, ob3,
                                         perm, PK, out);
}